// Round 7
// baseline (1558.732 us; speedup 1.0000x reference)
//
#include <hip/hip_runtime.h>
#include <math.h>

namespace {

constexpr int kB   = 8;
constexpr int kL   = 256;
constexpr int kTok = 2048;   // B*L
constexpr int kDM  = 384;
constexpr int kDI  = 768;
constexpr int kDS  = 16;
constexpr int kDTR = 24;
constexpr int kPROJ = 56;    // DTR + 2*DS
constexpr int kNL  = 12;

constexpr int kWIN  = 2 * kDI * kDM;   // 589824 in_proj weights/layer
constexpr int kWOUT = kDM * kDI;       // 294912
constexpr int kWX   = kPROJ * kDI;     // 43008
constexpr int kWTOT = kWIN + kWOUT + kWX;  // 927744

typedef float f32x4 __attribute__((ext_vector_type(4)));
typedef short short8 __attribute__((ext_vector_type(8)));

__device__ __forceinline__ float softplus_f(float x) {
  return (x > 20.f) ? x : log1pf(__expf(x));
}
__device__ __forceinline__ float silu_f(float x) {
  return x / (1.f + __expf(-x));
}
__device__ __forceinline__ unsigned short f2bf(float f) {
  union { float f; unsigned u; } v; v.f = f;
  unsigned r = v.u + 0x7FFFu + ((v.u >> 16) & 1u);
  return (unsigned short)(r >> 16);
}

// ------------- patch embed GEMM: tok = im2col(x)·patch_w^T + b + pos -------
__global__ __launch_bounds__(256) void patch_gemm_k(
    const float* __restrict__ x, const float* __restrict__ Bw,
    const float* __restrict__ bias, const float* __restrict__ pos,
    float* __restrict__ C) {
  __shared__ float As[16][68];
  __shared__ float Bs[16][68];
  int tid = threadIdx.x;
  int bm = blockIdx.y * 64;
  int bn = blockIdx.x * 64;
  int lr = tid >> 2;
  int lk = (tid & 3) << 2;
  int tm = (tid >> 4) << 2;
  int tn = (tid & 15) << 2;
  float acc[4][4] = {};
  for (int k0 = 0; k0 < 256; k0 += 16) {
    {
      int token = bm + lr;
      int b = token >> 8, l = token & 255;
      int h = l >> 3, w = l & 7;
      int p = k0 >> 4;
      const float* ap = x + ((size_t)(b * 512) + h * 16 + p) * 128 + w * 16 + lk;
      float4 av = *(const float4*)ap;
      As[lk + 0][lr] = av.x; As[lk + 1][lr] = av.y;
      As[lk + 2][lr] = av.z; As[lk + 3][lr] = av.w;
    }
    {
      const float* bp = Bw + (size_t)(bn + lr) * 256 + k0 + lk;
      float4 bv = *(const float4*)bp;
      Bs[lk + 0][lr] = bv.x; Bs[lk + 1][lr] = bv.y;
      Bs[lk + 2][lr] = bv.z; Bs[lk + 3][lr] = bv.w;
    }
    __syncthreads();
    #pragma unroll
    for (int k = 0; k < 16; ++k) {
      float4 a = *(const float4*)&As[k][tm];
      float4 b = *(const float4*)&Bs[k][tn];
      float av[4] = {a.x, a.y, a.z, a.w};
      float bv[4] = {b.x, b.y, b.z, b.w};
      #pragma unroll
      for (int i = 0; i < 4; ++i)
        #pragma unroll
        for (int j = 0; j < 4; ++j)
          acc[i][j] = fmaf(av[i], bv[j], acc[i][j]);
    }
    __syncthreads();
  }
  #pragma unroll
  for (int i = 0; i < 4; ++i) {
    int row = bm + tm + i;
    #pragma unroll
    for (int j = 0; j < 4; ++j) {
      int col = bn + tn + j;
      C[(size_t)row * kDM + col] =
          acc[i][j] + bias[col] + pos[(size_t)(row & 255) * kDM + col];
    }
  }
}

// ------------- final layernorm (fp32 out) ----------------------------------
__global__ __launch_bounds__(384) void ln_k(
    const float* __restrict__ in, float* __restrict__ outv,
    const float* __restrict__ g, const float* __restrict__ bb) {
  int t = blockIdx.x, d = threadIdx.x;
  float v = in[(size_t)t * kDM + d];
  float s = v, s2 = v * v;
  #pragma unroll
  for (int m = 32; m >= 1; m >>= 1) {
    s  += __shfl_xor(s, m);
    s2 += __shfl_xor(s2, m);
  }
  __shared__ float ps[6], ps2[6];
  if ((d & 63) == 0) { ps[d >> 6] = s; ps2[d >> 6] = s2; }
  __syncthreads();
  float S = 0.f, S2 = 0.f;
  #pragma unroll
  for (int i = 0; i < 6; ++i) { S += ps[i]; S2 += ps2[i]; }
  float mean = S * (1.f / 384.f);
  float var  = S2 * (1.f / 384.f) - mean * mean;
  float r = rsqrtf(var + 1e-5f);
  outv[(size_t)t * kDM + d] = (v - mean) * r * g[d] + bb[d];
}

// ------------- convert ALL layers' GEMM weights fp32 -> bf16 ---------------
__global__ __launch_bounds__(256) void convert_all_k(
    const float* __restrict__ w_in, const float* __restrict__ w_out,
    const float* __restrict__ w_x, unsigned short* __restrict__ dst) {
  int layer = blockIdx.y;
  int i4 = (blockIdx.x * 256 + threadIdx.x) * 4;
  if (i4 >= kWTOT) return;
  const float* src;
  int off;
  if (i4 < kWIN) { src = w_in + (size_t)layer * kWIN; off = i4; }
  else if (i4 < kWIN + kWOUT) { src = w_out + (size_t)layer * kWOUT; off = i4 - kWIN; }
  else { src = w_x + (size_t)layer * kWX; off = i4 - kWIN - kWOUT; }
  float4 v = *(const float4*)(src + off);
  unsigned short o[4] = {f2bf(v.x), f2bf(v.y), f2bf(v.z), f2bf(v.w)};
  *(uint2*)(dst + (size_t)layer * kWTOT + i4) = *(const uint2*)o;
}

// ------------- in_proj with fused LayerNorm --------------------------------
// C[2048,1536] = LN(tok)[2048,384] · W[1536,384]^T   (bf16 MFMA, fp32 out)
__global__ __launch_bounds__(256) void inproj_ln_k(
    const float* __restrict__ tok, const unsigned short* __restrict__ Bw,
    const float* __restrict__ g, const float* __restrict__ bb,
    float* __restrict__ C) {
  __shared__ __align__(16) unsigned short As[4][128][8];
  __shared__ __align__(16) unsigned short Bs[4][128][8];
  __shared__ float smean[128], srstd[128];
  __shared__ float sg_[kDM], sb_[kDM];
  int tid = threadIdx.x;
  int bm = blockIdx.y * 128;
  int bn = blockIdx.x * 128;
  for (int i = tid; i < kDM; i += 256) { sg_[i] = g[i]; sb_[i] = bb[i]; }
  // LN stats prepass: 2 threads per row
  {
    int r = tid >> 1, half = tid & 1;
    const float* rp = tok + (size_t)(bm + r) * kDM + half * 192;
    float s = 0.f, s2 = 0.f;
    #pragma unroll
    for (int q = 0; q < 48; ++q) {
      float4 v = ((const float4*)rp)[q];
      s  += v.x + v.y + v.z + v.w;
      s2 += v.x * v.x + v.y * v.y + v.z * v.z + v.w * v.w;
    }
    s  += __shfl_xor(s, 1);
    s2 += __shfl_xor(s2, 1);
    if (half == 0) {
      float mean = s * (1.f / 384.f);
      float var  = s2 * (1.f / 384.f) - mean * mean;
      smean[r] = mean;
      srstd[r] = rsqrtf(var + 1e-5f);
    }
  }
  __syncthreads();
  int wave = tid >> 6, lane = tid & 63;
  int lm = lane & 15, lq = lane >> 4;
  int wm = (wave >> 1) * 64, wn = (wave & 1) * 64;
  f32x4 acc[4][4] = {};
  for (int k0 = 0; k0 < kDM; k0 += 32) {
    int ar0 = tid & 127, aq0 = tid >> 7;  // aq0 in {0,1}; handles kq {aq0, aq0+2}
    unsigned short av[2][8];
    float mean = smean[ar0], rstd = srstd[ar0];
    #pragma unroll
    for (int gq = 0; gq < 2; ++gq) {
      int kq = aq0 + gq * 2;
      const float* ap = tok + (size_t)(bm + ar0) * kDM + k0 + kq * 8;
      float4 v0 = ((const float4*)ap)[0];
      float4 v1 = ((const float4*)ap)[1];
      float vv[8] = {v0.x, v0.y, v0.z, v0.w, v1.x, v1.y, v1.z, v1.w};
      #pragma unroll
      for (int j = 0; j < 8; ++j) {
        int k = k0 + kq * 8 + j;
        av[gq][j] = f2bf((vv[j] - mean) * rstd * sg_[k] + sb_[k]);
      }
    }
    uint4 b0 = *(const uint4*)(Bw + (size_t)(bn + ar0) * kDM + k0 + aq0 * 8);
    uint4 b1 = *(const uint4*)(Bw + (size_t)(bn + ar0) * kDM + k0 + (aq0 + 2) * 8);
    __syncthreads();
    *(uint4*)&As[aq0][ar0][0]     = *(const uint4*)av[0];
    *(uint4*)&As[aq0 + 2][ar0][0] = *(const uint4*)av[1];
    *(uint4*)&Bs[aq0][ar0][0]     = b0;
    *(uint4*)&Bs[aq0 + 2][ar0][0] = b1;
    __syncthreads();
    short8 bfrag[4];
    #pragma unroll
    for (int ni = 0; ni < 4; ++ni)
      bfrag[ni] = *(const short8*)&Bs[lq][wn + ni * 16 + lm][0];
    #pragma unroll
    for (int mi = 0; mi < 4; ++mi) {
      short8 afrag = *(const short8*)&As[lq][wm + mi * 16 + lm][0];
      #pragma unroll
      for (int ni = 0; ni < 4; ++ni)
        acc[mi][ni] = __builtin_amdgcn_mfma_f32_16x16x32_bf16(
            afrag, bfrag[ni], acc[mi][ni], 0, 0, 0);
    }
  }
  #pragma unroll
  for (int mi = 0; mi < 4; ++mi) {
    #pragma unroll
    for (int ni = 0; ni < 4; ++ni) {
      int grow0 = bm + wm + mi * 16 + lq * 4;
      int gcol = bn + wn + ni * 16 + lm;
      #pragma unroll
      for (int r = 0; r < 4; ++r)
        C[(size_t)(grow0 + r) * (2 * kDI) + gcol] = acc[mi][ni][r];
    }
  }
}

// ------------- bf16 MFMA NT GEMM: C[M,N] fp32 = A[M,K]·B[N,K]^T ------------
// EPIL 0: plain store. EPIL 1: atomicAdd (split-K / residual).
template <int BN, int EPIL>
__global__ __launch_bounds__(256) void bgemm_k(
    const unsigned short* __restrict__ A, int lda,
    const unsigned short* __restrict__ B, int ldb,
    float* __restrict__ C, int ldc, int N, int Kc) {
  __shared__ __align__(16) unsigned short As[4][128][8];
  __shared__ __align__(16) unsigned short Bs[4][BN][8];
  int tid = threadIdx.x;
  int bm = blockIdx.y * 128;
  int bn = blockIdx.x * BN;
  int k_begin = blockIdx.z * Kc;
  int wave = tid >> 6, lane = tid & 63;
  int lm = lane & 15, lq = lane >> 4;
  int wm, wn;
  if (BN == 128) { wm = (wave >> 1) * 64; wn = (wave & 1) * 64; }
  else           { wm = wave * 32;        wn = 0; }
  constexpr int MT = (BN == 128) ? 4 : 2;
  f32x4 acc[MT][4] = {};

  for (int kt = 0; kt < Kc; kt += 32) {
    int k0 = k_begin + kt;
    int ar0 = tid & 127, aq0 = tid >> 7;
    int aq1 = aq0 + 2;
    uint4 a0 = *(const uint4*)(A + (size_t)(bm + ar0) * lda + k0 + aq0 * 8);
    uint4 a1 = *(const uint4*)(A + (size_t)(bm + ar0) * lda + k0 + aq1 * 8);
    uint4 b0, b1;
    int br0, bq0, br1 = 0, bq1 = 0;
    if (BN == 128) {
      br0 = tid & 127; bq0 = tid >> 7; br1 = br0; bq1 = bq0 + 2;
      b0 = *(const uint4*)(B + (size_t)(bn + br0) * ldb + k0 + bq0 * 8);
      b1 = *(const uint4*)(B + (size_t)(bn + br1) * ldb + k0 + bq1 * 8);
    } else {
      br0 = tid & 63; bq0 = tid >> 6;
      if (bn + br0 < N)
        b0 = *(const uint4*)(B + (size_t)(bn + br0) * ldb + k0 + bq0 * 8);
      else
        b0 = make_uint4(0u, 0u, 0u, 0u);
    }
    __syncthreads();
    *(uint4*)&As[aq0][ar0][0] = a0;
    *(uint4*)&As[aq1][ar0][0] = a1;
    *(uint4*)&Bs[bq0][br0][0] = b0;
    if (BN == 128) *(uint4*)&Bs[bq1][br1][0] = b1;
    __syncthreads();

    short8 bfrag[4];
    #pragma unroll
    for (int ni = 0; ni < 4; ++ni)
      bfrag[ni] = *(const short8*)&Bs[lq][wn + ni * 16 + lm][0];
    #pragma unroll
    for (int mi = 0; mi < MT; ++mi) {
      short8 afrag = *(const short8*)&As[lq][wm + mi * 16 + lm][0];
      #pragma unroll
      for (int ni = 0; ni < 4; ++ni)
        acc[mi][ni] = __builtin_amdgcn_mfma_f32_16x16x32_bf16(
            afrag, bfrag[ni], acc[mi][ni], 0, 0, 0);
    }
  }

  #pragma unroll
  for (int mi = 0; mi < MT; ++mi) {
    #pragma unroll
    for (int ni = 0; ni < 4; ++ni) {
      int grow0 = bm + wm + mi * 16 + lq * 4;
      int gcol = bn + wn + ni * 16 + lm;
      #pragma unroll
      for (int r = 0; r < 4; ++r) {
        float v = acc[mi][ni][r];
        int grow = grow0 + r;
        if (EPIL == 0) {
          C[(size_t)grow * ldc + gcol] = v;
        } else {
          if (gcol < N) atomicAdd(&C[(size_t)grow * ldc + gcol], v);
        }
      }
    }
  }
}

// ------------- causal depthwise conv (DC=4) + SiLU + z-gate + proj zero ----
__global__ __launch_bounds__(256) void conv_tr_k(
    const float* __restrict__ xz, const float* __restrict__ cw,
    const float* __restrict__ cb, float* __restrict__ uT,
    float* __restrict__ sgT, unsigned short* __restrict__ u_bf,
    float* __restrict__ proj_zero) {
  int b = blockIdx.y;
  int l0 = blockIdx.x * 16;
  int tid = threadIdx.x;
  // zero proj for the upcoming split-K atomics (grid covers 32768 threads)
  {
    int gid = (blockIdx.y * 16 + blockIdx.x) * 256 + tid;
    for (int i = gid; i < kTok * kPROJ; i += 16 * kB * 256) proj_zero[i] = 0.f;
  }
  #pragma unroll
  for (int ch = 0; ch < 3; ++ch) {
    int d = ch * 256 + tid;
    float w0 = cw[d * 4], w1 = cw[d * 4 + 1], w2 = cw[d * 4 + 2], w3 = cw[d * 4 + 3];
    float bias = cb[d];
    float v[19];
    #pragma unroll
    for (int j = 0; j < 19; ++j) {
      int l = l0 - 3 + j;
      v[j] = (l >= 0) ? xz[(size_t)(b * kL + l) * (2 * kDI) + d] : 0.f;
    }
    float* up = uT + ((size_t)b * kDI + d) * kL + l0;
    float* sp = sgT + ((size_t)b * kDI + d) * kL + l0;
    #pragma unroll
    for (int i = 0; i < 16; ++i) {
      float acc = bias;
      acc = fmaf(v[i], w0, acc);
      acc = fmaf(v[i + 1], w1, acc);
      acc = fmaf(v[i + 2], w2, acc);
      acc = fmaf(v[i + 3], w3, acc);
      float o = silu_f(acc);
      up[i] = o;
      u_bf[(size_t)(b * kL + l0 + i) * kDI + d] = f2bf(o);
      float zv = xz[(size_t)(b * kL + l0 + i) * (2 * kDI) + kDI + d];
      sp[i] = silu_f(zv);
    }
  }
}

// ------------- fused dt_proj + chunked selective scan, 8 d's per block -----
// proj[t][56] row-major (0:24 dt, 24:40 B, 40:56 C). Emits y_bf[token][768]
// bf16 directly (8 consecutive d = one uint4 per token) - no transpose pass.
__global__ __launch_bounds__(256) void scan8_k(
    const float* __restrict__ proj, const float* __restrict__ uT,
    const float* __restrict__ sgT, const float* __restrict__ dtw,
    const float* __restrict__ dtb, const float* __restrict__ A_log,
    const float* __restrict__ Dsk, unsigned short* __restrict__ y_bf) {
  int d0 = blockIdx.x * 8;
  int b = blockIdx.y;
  int tid = threadIdx.x;
  int c = tid >> 4, n = tid & 15;
  __shared__ float sBC[256][33];    // [l][0:16]=B[n], [16:32]=C[n]
  __shared__ float sdall[8][256];   // delta per (dd, l)
  __shared__ float su[256], sg[256];
  __shared__ float sh_h[16][17], sh_a[16][17];
  __shared__ float swdt[8][24];
  __shared__ float sAv[8][16];
  __shared__ float sbdt[8], sDv[8];
  __shared__ unsigned short sy[256][8];

  {
    const float* pr = proj + ((size_t)(b * kL) + tid) * kPROJ + 24;
    #pragma unroll
    for (int q = 0; q < 8; ++q)
      *(float4*)&sBC[tid][q * 4] = ((const float4*)pr)[q];
  }
  if (tid < 192) swdt[tid / 24][tid % 24] =
      dtw[(size_t)(d0 + tid / 24) * kDTR + (tid % 24)];
  if (tid < 128) sAv[tid >> 4][tid & 15] =
      -__expf(A_log[(size_t)(d0 + (tid >> 4)) * kDS + (tid & 15)]);
  if (tid < 8) { sbdt[tid] = dtb[d0 + tid]; sDv[tid] = Dsk[d0 + tid]; }
  __syncthreads();

  // delta for all 8 d's at l = tid
  {
    const float* pr = proj + ((size_t)(b * kL) + tid) * kPROJ;
    float p[24];
    #pragma unroll
    for (int q = 0; q < 6; ++q) {
      float4 v = ((const float4*)pr)[q];
      p[q * 4] = v.x; p[q * 4 + 1] = v.y; p[q * 4 + 2] = v.z; p[q * 4 + 3] = v.w;
    }
    #pragma unroll
    for (int dd = 0; dd < 8; ++dd) {
      float acc = sbdt[dd];
      #pragma unroll
      for (int r = 0; r < 24; ++r) acc = fmaf(p[r], swdt[dd][r], acc);
      sdall[dd][tid] = softplus_f(acc);
    }
  }
  __syncthreads();

  for (int dd = 0; dd < 8; ++dd) {
    int d = d0 + dd;
    size_t rbase = ((size_t)b * kDI + d) * kL;
    su[tid] = uT[rbase + tid];
    sg[tid] = sgT[rbase + tid];
    float Av = sAv[dd][n];
    __syncthreads();
    float h = 0.f, ca = 1.f;
    float h_reg[16], ca_reg[16];
    #pragma unroll
    for (int i = 0; i < 16; ++i) {
      int l = c * 16 + i;
      float dl = sdall[dd][l];
      float a = __expf(dl * Av);
      h = fmaf(a, h, (dl * su[l]) * sBC[l][n]);
      ca *= a;
      h_reg[i] = h; ca_reg[i] = ca;
    }
    sh_h[c][n] = h; sh_a[c][n] = ca;
    __syncthreads();
    float h0 = 0.f;
    for (int j = 0; j < c; ++j) h0 = fmaf(sh_a[j][n], h0, sh_h[j][n]);
    float Dv = sDv[dd];
    #pragma unroll
    for (int i = 0; i < 16; ++i) {
      int l = c * 16 + i;
      float yv = fmaf(ca_reg[i], h0, h_reg[i]) * sBC[l][16 + n];
      yv += __shfl_xor(yv, 1);
      yv += __shfl_xor(yv, 2);
      yv += __shfl_xor(yv, 4);
      yv += __shfl_xor(yv, 8);
      if (n == 0) sy[l][dd] = f2bf((yv + su[l] * Dv) * sg[l]);
    }
    __syncthreads();
  }
  *(uint4*)(y_bf + ((size_t)(b * kL) + tid) * kDI + d0) = *(const uint4*)&sy[tid][0];
}

// ---------------- mean pool over L ----------------
__global__ __launch_bounds__(384) void pool_k(
    const float* __restrict__ h, float* __restrict__ pooled) {
  int b = blockIdx.x, d = threadIdx.x;
  float acc = 0.f;
  for (int l = 0; l < kL; ++l) acc += h[(size_t)(b * kL + l) * kDM + d];
  pooled[b * kDM + d] = acc * (1.f / 256.f);
}

// ---------------- head ----------------
__global__ __launch_bounds__(64) void head_k(
    const float* __restrict__ pooled, const float* __restrict__ hw,
    const float* __restrict__ hb, float* __restrict__ out) {
  int b = blockIdx.x >> 2, c = blockIdx.x & 3;
  int lane = threadIdx.x;
  float acc = 0.f;
  for (int dd = lane; dd < kDM; dd += 64)
    acc = fmaf(pooled[b * kDM + dd], hw[c * kDM + dd], acc);
  #pragma unroll
  for (int m = 32; m >= 1; m >>= 1) acc += __shfl_xor(acc, m);
  if (lane == 0) out[b * 4 + c] = acc + hb[c];
}

}  // namespace

extern "C" void kernel_launch(void* const* d_in, const int* in_sizes, int n_in,
                              void* d_out, int out_size, void* d_ws, size_t ws_size,
                              hipStream_t stream) {
  (void)in_sizes; (void)n_in; (void)out_size; (void)ws_size;
  const float* x        = (const float*)d_in[0];
  const float* patch_w  = (const float*)d_in[1];
  const float* patch_b  = (const float*)d_in[2];
  const float* pos      = (const float*)d_in[3];
  const float* ln_g     = (const float*)d_in[4];
  const float* ln_b     = (const float*)d_in[5];
  const float* in_w     = (const float*)d_in[6];
  const float* conv_w   = (const float*)d_in[7];
  const float* conv_b   = (const float*)d_in[8];
  const float* xproj_w  = (const float*)d_in[9];
  const float* dtproj_w = (const float*)d_in[10];
  const float* dtproj_b = (const float*)d_in[11];
  const float* A_log    = (const float*)d_in[12];
  const float* Dskip    = (const float*)d_in[13];
  const float* out_w    = (const float*)d_in[14];
  const float* fn_g     = (const float*)d_in[15];
  const float* fn_b     = (const float*)d_in[16];
  const float* head_w   = (const float*)d_in[17];
  const float* head_b   = (const float*)d_in[18];
  float* out = (float*)d_out;

  float* ws = (float*)d_ws;
  float* tok    = ws; ws += kTok * kDM;       // fp32 residual
  float* xz     = ws; ws += kTok * 2 * kDI;
  float* uT     = ws; ws += kTok * kDI;
  float* sgT    = ws; ws += kTok * kDI;
  float* proj   = ws; ws += kTok * kPROJ;     // [t][56] row-major
  float* pooled = ws; ws += kB * kDM;
  unsigned short* y_bf = (unsigned short*)ws; ws += kTok * kDI / 2;
  unsigned short* u_bf = (unsigned short*)ws; ws += kTok * kDI / 2;
  unsigned short* w_bf = (unsigned short*)ws; ws += (size_t)kNL * kWTOT / 2;
  float* lnout = xz;  // overlay: xz dead after last conv

  // all-layer weight cast (once per call)
  convert_all_k<<<dim3(kWTOT / 4 / 256, kNL), 256, 0, stream>>>(
      in_w, out_w, xproj_w, w_bf);

  // Patch embedding fused: im2col + GEMM + bias + pos
  patch_gemm_k<<<dim3(6, 32), 256, 0, stream>>>(x, patch_w, patch_b, pos, tok);

  for (int layer = 0; layer < kNL; ++layer) {
    const unsigned short* wl = w_bf + (size_t)layer * kWTOT;
    // in_proj with fused LN: LN(tok)[2048,384] x [1536,384]^T -> xz fp32
    inproj_ln_k<<<dim3(12, 16), 256, 0, stream>>>(
        tok, wl, ln_g + layer * kDM, ln_b + layer * kDM, xz);
    // depthwise causal conv + SiLU + z-gate (+ proj zeroing)
    conv_tr_k<<<dim3(16, kB), 256, 0, stream>>>(
        xz, conv_w + layer * kDI * 4, conv_b + layer * kDI, uT, sgT, u_bf, proj);
    // x_proj (MFMA, split-K=6, atomic): [2048,768]x[56,768]^T -> proj[t][56]
    bgemm_k<64, 1><<<dim3(1, 16, 6), 256, 0, stream>>>(
        u_bf, kDI, wl + kWIN + kWOUT, kDI, proj, kPROJ, kPROJ, kDI / 6);
    // fused dt_proj + selective scan (8 d/block) -> y_bf[token][768] bf16
    scan8_k<<<dim3(kDI / 8, kB), 256, 0, stream>>>(
        proj, uT, sgT, dtproj_w + (size_t)layer * kDI * kDTR,
        dtproj_b + layer * kDI, A_log + (size_t)layer * kDI * kDS,
        Dskip + layer * kDI, y_bf);
    // out_proj (MFMA, split-K=2, atomic into residual): tok += y x W^T
    bgemm_k<128, 1><<<dim3(3, 16, 2), 256, 0, stream>>>(
        y_bf, kDI, wl + kWIN, kDI, tok, kDM, kDM, kDI / 2);
  }

  ln_k<<<kTok, kDM, 0, stream>>>(tok, lnout, fn_g, fn_b);
  pool_k<<<kB, kDM, 0, stream>>>(lnout, pooled);
  head_k<<<kB * 4, 64, 0, stream>>>(pooled, head_w, head_b, out);
}

// Round 8
// 1435.494 us; speedup vs baseline: 1.0859x; 1.0859x over previous
//
#include <hip/hip_runtime.h>
#include <math.h>

namespace {

constexpr int kB   = 8;
constexpr int kL   = 256;
constexpr int kTok = 2048;   // B*L
constexpr int kDM  = 384;
constexpr int kDI  = 768;
constexpr int kDS  = 16;
constexpr int kDTR = 24;
constexpr int kPROJ = 56;    // DTR + 2*DS
constexpr int kNL  = 12;

constexpr int kWIN  = 2 * kDI * kDM;   // 589824 in_proj weights/layer
constexpr int kWOUT = kDM * kDI;       // 294912
constexpr int kWX   = kPROJ * kDI;     // 43008
constexpr int kWTOT = kWIN + kWOUT + kWX;  // 927744

typedef float f32x4 __attribute__((ext_vector_type(4)));
typedef short short8 __attribute__((ext_vector_type(8)));

__device__ __forceinline__ float softplus_f(float x) {
  return (x > 20.f) ? x : log1pf(__expf(x));
}
__device__ __forceinline__ float silu_f(float x) {
  return x / (1.f + __expf(-x));
}
__device__ __forceinline__ unsigned short f2bf(float f) {
  union { float f; unsigned u; } v; v.f = f;
  unsigned r = v.u + 0x7FFFu + ((v.u >> 16) & 1u);
  return (unsigned short)(r >> 16);
}

// ------------- patch embed GEMM: tok = im2col(x)·patch_w^T + b + pos -------
__global__ __launch_bounds__(256) void patch_gemm_k(
    const float* __restrict__ x, const float* __restrict__ Bw,
    const float* __restrict__ bias, const float* __restrict__ pos,
    float* __restrict__ C) {
  __shared__ float As[16][68];
  __shared__ float Bs[16][68];
  int tid = threadIdx.x;
  int bm = blockIdx.y * 64;
  int bn = blockIdx.x * 64;
  int lr = tid >> 2;
  int lk = (tid & 3) << 2;
  int tm = (tid >> 4) << 2;
  int tn = (tid & 15) << 2;
  float acc[4][4] = {};
  for (int k0 = 0; k0 < 256; k0 += 16) {
    {
      int token = bm + lr;
      int b = token >> 8, l = token & 255;
      int h = l >> 3, w = l & 7;
      int p = k0 >> 4;
      const float* ap = x + ((size_t)(b * 512) + h * 16 + p) * 128 + w * 16 + lk;
      float4 av = *(const float4*)ap;
      As[lk + 0][lr] = av.x; As[lk + 1][lr] = av.y;
      As[lk + 2][lr] = av.z; As[lk + 3][lr] = av.w;
    }
    {
      const float* bp = Bw + (size_t)(bn + lr) * 256 + k0 + lk;
      float4 bv = *(const float4*)bp;
      Bs[lk + 0][lr] = bv.x; Bs[lk + 1][lr] = bv.y;
      Bs[lk + 2][lr] = bv.z; Bs[lk + 3][lr] = bv.w;
    }
    __syncthreads();
    #pragma unroll
    for (int k = 0; k < 16; ++k) {
      float4 a = *(const float4*)&As[k][tm];
      float4 b = *(const float4*)&Bs[k][tn];
      float av[4] = {a.x, a.y, a.z, a.w};
      float bv[4] = {b.x, b.y, b.z, b.w};
      #pragma unroll
      for (int i = 0; i < 4; ++i)
        #pragma unroll
        for (int j = 0; j < 4; ++j)
          acc[i][j] = fmaf(av[i], bv[j], acc[i][j]);
    }
    __syncthreads();
  }
  #pragma unroll
  for (int i = 0; i < 4; ++i) {
    int row = bm + tm + i;
    #pragma unroll
    for (int j = 0; j < 4; ++j) {
      int col = bn + tn + j;
      C[(size_t)row * kDM + col] =
          acc[i][j] + bias[col] + pos[(size_t)(row & 255) * kDM + col];
    }
  }
}

// ------------- layernorm over DM=384; bf16 out; optionally zero proj -------
template <bool BF16OUT>
__global__ __launch_bounds__(384) void ln_k(
    const float* __restrict__ in, void* __restrict__ outv,
    const float* __restrict__ g, const float* __restrict__ bb,
    float* __restrict__ proj_zero) {
  int t = blockIdx.x, d = threadIdx.x;
  if (proj_zero && d < kPROJ) proj_zero[(size_t)t * kPROJ + d] = 0.f;
  float v = in[(size_t)t * kDM + d];
  float s = v, s2 = v * v;
  #pragma unroll
  for (int m = 32; m >= 1; m >>= 1) {
    s  += __shfl_xor(s, m);
    s2 += __shfl_xor(s2, m);
  }
  __shared__ float ps[6], ps2[6];
  if ((d & 63) == 0) { ps[d >> 6] = s; ps2[d >> 6] = s2; }
  __syncthreads();
  float S = 0.f, S2 = 0.f;
  #pragma unroll
  for (int i = 0; i < 6; ++i) { S += ps[i]; S2 += ps2[i]; }
  float mean = S * (1.f / 384.f);
  float var  = S2 * (1.f / 384.f) - mean * mean;
  float r = rsqrtf(var + 1e-5f);
  float o = (v - mean) * r * g[d] + bb[d];
  if (BF16OUT) ((unsigned short*)outv)[(size_t)t * kDM + d] = f2bf(o);
  else ((float*)outv)[(size_t)t * kDM + d] = o;
}

// ------------- convert ALL layers' GEMM weights fp32 -> bf16 ---------------
__global__ __launch_bounds__(256) void convert_all_k(
    const float* __restrict__ w_in, const float* __restrict__ w_out,
    const float* __restrict__ w_x, unsigned short* __restrict__ dst) {
  int layer = blockIdx.y;
  int i4 = (blockIdx.x * 256 + threadIdx.x) * 4;
  if (i4 >= kWTOT) return;
  const float* src;
  int off;
  if (i4 < kWIN) { src = w_in + (size_t)layer * kWIN; off = i4; }
  else if (i4 < kWIN + kWOUT) { src = w_out + (size_t)layer * kWOUT; off = i4 - kWIN; }
  else { src = w_x + (size_t)layer * kWX; off = i4 - kWIN - kWOUT; }
  float4 v = *(const float4*)(src + off);
  unsigned short o[4] = {f2bf(v.x), f2bf(v.y), f2bf(v.z), f2bf(v.w)};
  *(uint2*)(dst + (size_t)layer * kWTOT + i4) = *(const uint2*)o;
}

// ------------- bf16 MFMA NT GEMM: C[M,N] fp32 = A[M,K]·B[N,K]^T ------------
// EPIL 0: plain store. EPIL 1: atomicAdd (split-K / residual).
template <int BN, int EPIL>
__global__ __launch_bounds__(256) void bgemm_k(
    const unsigned short* __restrict__ A, int lda,
    const unsigned short* __restrict__ B, int ldb,
    float* __restrict__ C, int ldc, int N, int Kc) {
  __shared__ __align__(16) unsigned short As[4][128][8];
  __shared__ __align__(16) unsigned short Bs[4][BN][8];
  int tid = threadIdx.x;
  int bm = blockIdx.y * 128;
  int bn = blockIdx.x * BN;
  int k_begin = blockIdx.z * Kc;
  int wave = tid >> 6, lane = tid & 63;
  int lm = lane & 15, lq = lane >> 4;
  int wm, wn;
  if (BN == 128) { wm = (wave >> 1) * 64; wn = (wave & 1) * 64; }
  else           { wm = wave * 32;        wn = 0; }
  constexpr int MT = (BN == 128) ? 4 : 2;
  f32x4 acc[MT][4] = {};

  for (int kt = 0; kt < Kc; kt += 32) {
    int k0 = k_begin + kt;
    int ar0 = tid & 127, aq0 = tid >> 7;
    int aq1 = aq0 + 2;
    uint4 a0 = *(const uint4*)(A + (size_t)(bm + ar0) * lda + k0 + aq0 * 8);
    uint4 a1 = *(const uint4*)(A + (size_t)(bm + ar0) * lda + k0 + aq1 * 8);
    uint4 b0, b1;
    int br0, bq0, br1 = 0, bq1 = 0;
    if (BN == 128) {
      br0 = tid & 127; bq0 = tid >> 7; br1 = br0; bq1 = bq0 + 2;
      b0 = *(const uint4*)(B + (size_t)(bn + br0) * ldb + k0 + bq0 * 8);
      b1 = *(const uint4*)(B + (size_t)(bn + br1) * ldb + k0 + bq1 * 8);
    } else {
      br0 = tid & 63; bq0 = tid >> 6;
      if (bn + br0 < N)
        b0 = *(const uint4*)(B + (size_t)(bn + br0) * ldb + k0 + bq0 * 8);
      else
        b0 = make_uint4(0u, 0u, 0u, 0u);
    }
    __syncthreads();
    *(uint4*)&As[aq0][ar0][0] = a0;
    *(uint4*)&As[aq1][ar0][0] = a1;
    *(uint4*)&Bs[bq0][br0][0] = b0;
    if (BN == 128) *(uint4*)&Bs[bq1][br1][0] = b1;
    __syncthreads();

    short8 bfrag[4];
    #pragma unroll
    for (int ni = 0; ni < 4; ++ni)
      bfrag[ni] = *(const short8*)&Bs[lq][wn + ni * 16 + lm][0];
    #pragma unroll
    for (int mi = 0; mi < MT; ++mi) {
      short8 afrag = *(const short8*)&As[lq][wm + mi * 16 + lm][0];
      #pragma unroll
      for (int ni = 0; ni < 4; ++ni)
        acc[mi][ni] = __builtin_amdgcn_mfma_f32_16x16x32_bf16(
            afrag, bfrag[ni], acc[mi][ni], 0, 0, 0);
    }
  }

  #pragma unroll
  for (int mi = 0; mi < MT; ++mi) {
    #pragma unroll
    for (int ni = 0; ni < 4; ++ni) {
      int grow0 = bm + wm + mi * 16 + lq * 4;
      int gcol = bn + wn + ni * 16 + lm;
      #pragma unroll
      for (int r = 0; r < 4; ++r) {
        float v = acc[mi][ni][r];
        int grow = grow0 + r;
        if (EPIL == 0) {
          C[(size_t)grow * ldc + gcol] = v;
        } else {
          if (gcol < N) atomicAdd(&C[(size_t)grow * ldc + gcol], v);
        }
      }
    }
  }
}

// ------------- causal depthwise conv (DC=4) + SiLU + z-gate ----------------
__global__ __launch_bounds__(256) void conv_tr_k(
    const float* __restrict__ xz, const float* __restrict__ cw,
    const float* __restrict__ cb, float* __restrict__ uT,
    float* __restrict__ sgT, unsigned short* __restrict__ u_bf) {
  int b = blockIdx.y;
  int l0 = blockIdx.x * 16;
  int tid = threadIdx.x;
  #pragma unroll
  for (int ch = 0; ch < 3; ++ch) {
    int d = ch * 256 + tid;
    float w0 = cw[d * 4], w1 = cw[d * 4 + 1], w2 = cw[d * 4 + 2], w3 = cw[d * 4 + 3];
    float bias = cb[d];
    float v[19];
    #pragma unroll
    for (int j = 0; j < 19; ++j) {
      int l = l0 - 3 + j;
      v[j] = (l >= 0) ? xz[(size_t)(b * kL + l) * (2 * kDI) + d] : 0.f;
    }
    float* up = uT + ((size_t)b * kDI + d) * kL + l0;
    float* sp = sgT + ((size_t)b * kDI + d) * kL + l0;
    #pragma unroll
    for (int i = 0; i < 16; ++i) {
      float acc = bias;
      acc = fmaf(v[i], w0, acc);
      acc = fmaf(v[i + 1], w1, acc);
      acc = fmaf(v[i + 2], w2, acc);
      acc = fmaf(v[i + 3], w3, acc);
      float o = silu_f(acc);
      up[i] = o;
      u_bf[(size_t)(b * kL + l0 + i) * kDI + d] = f2bf(o);
      float zv = xz[(size_t)(b * kL + l0 + i) * (2 * kDI) + kDI + d];
      sp[i] = silu_f(zv);
    }
  }
}

// ------------- fused dt_proj + chunked selective scan, 4 d's per block -----
// proj[t][56] row-major (0:24 dt, 24:40 B, 40:56 C). B/C kept in registers
// (reused across the 4 d's); u read directly from L1-hot global; delta for
// all 4 d's computed once into LDS. y emitted bf16 l-major (coalesced).
__global__ __launch_bounds__(256) void scan4_k(
    const float* __restrict__ proj, const float* __restrict__ uT,
    const float* __restrict__ sgT, const float* __restrict__ dtw,
    const float* __restrict__ dtb, const float* __restrict__ A_log,
    const float* __restrict__ Dsk, unsigned short* __restrict__ yT_bf) {
  int d0 = blockIdx.x * 4;
  int b = blockIdx.y;
  int tid = threadIdx.x;
  int c = tid >> 4, n = tid & 15;
  __shared__ float sdall[4][256];
  __shared__ float sh_h[16][17], sh_a[16][17];
  __shared__ float swdt[4][24];
  __shared__ float sAv[4][16];
  __shared__ float sbdt[4], sDv[4];
  __shared__ __align__(8) unsigned short sy[256];

  if (tid < 96) swdt[tid / 24][tid % 24] =
      dtw[(size_t)(d0 + tid / 24) * kDTR + (tid % 24)];
  if (tid < 64) sAv[tid >> 4][tid & 15] =
      -__expf(A_log[(size_t)(d0 + (tid >> 4)) * kDS + (tid & 15)]);
  if (tid < 4) { sbdt[tid] = dtb[d0 + tid]; sDv[tid] = Dsk[d0 + tid]; }

  // per-thread B/C for (c,n): l = c*16+i  (reused across all 4 d's)
  float B_[16], C_[16];
  {
    const float* pbl = proj + ((size_t)(b * kL) + c * 16) * kPROJ;
    #pragma unroll
    for (int i = 0; i < 16; ++i) {
      B_[i] = pbl[i * kPROJ + 24 + n];
      C_[i] = pbl[i * kPROJ + 40 + n];
    }
  }
  __syncthreads();

  // delta for l = tid, all 4 d's
  {
    const float* pr = proj + ((size_t)(b * kL) + tid) * kPROJ;
    float p[24];
    #pragma unroll
    for (int q = 0; q < 6; ++q) {
      float4 v = ((const float4*)pr)[q];
      p[q * 4] = v.x; p[q * 4 + 1] = v.y; p[q * 4 + 2] = v.z; p[q * 4 + 3] = v.w;
    }
    #pragma unroll
    for (int dd = 0; dd < 4; ++dd) {
      float acc = sbdt[dd];
      #pragma unroll
      for (int r = 0; r < 24; ++r) acc = fmaf(p[r], swdt[dd][r], acc);
      sdall[dd][tid] = softplus_f(acc);
    }
  }
  __syncthreads();

  #pragma unroll 1
  for (int dd = 0; dd < 4; ++dd) {
    int d = d0 + dd;
    size_t rbase = ((size_t)b * kDI + d) * kL;
    // u for this thread's 16 l's: direct global float4 (L1-hot, shared lines)
    float u_[16];
    {
      const float* up = uT + rbase + c * 16;
      #pragma unroll
      for (int q = 0; q < 4; ++q) {
        float4 v = ((const float4*)up)[q];
        u_[q * 4] = v.x; u_[q * 4 + 1] = v.y;
        u_[q * 4 + 2] = v.z; u_[q * 4 + 3] = v.w;
      }
    }
    float Av = sAv[dd][n];
    float h = 0.f, ca = 1.f;
    float h_reg[16], ca_reg[16];
    #pragma unroll
    for (int i = 0; i < 16; ++i) {
      float dl = sdall[dd][c * 16 + i];
      float a = __expf(dl * Av);
      h = fmaf(a, h, (dl * u_[i]) * B_[i]);
      ca *= a;
      h_reg[i] = h; ca_reg[i] = ca;
    }
    sh_h[c][n] = h; sh_a[c][n] = ca;
    __syncthreads();
    float h0 = 0.f;
    for (int j = 0; j < c; ++j) h0 = fmaf(sh_a[j][n], h0, sh_h[j][n]);

    float sg_[16];
    if (n == 0) {
      const float* sp = sgT + rbase + c * 16;
      #pragma unroll
      for (int q = 0; q < 4; ++q) {
        float4 v = ((const float4*)sp)[q];
        sg_[q * 4] = v.x; sg_[q * 4 + 1] = v.y;
        sg_[q * 4 + 2] = v.z; sg_[q * 4 + 3] = v.w;
      }
    }
    float Dv = sDv[dd];
    #pragma unroll
    for (int i = 0; i < 16; ++i) {
      float yv = fmaf(ca_reg[i], h0, h_reg[i]) * C_[i];
      yv += __shfl_xor(yv, 1);
      yv += __shfl_xor(yv, 2);
      yv += __shfl_xor(yv, 4);
      yv += __shfl_xor(yv, 8);
      if (n == 0) sy[c * 16 + i] = f2bf((yv + u_[i] * Dv) * sg_[i]);
    }
    __syncthreads();
    yT_bf[rbase + tid] = sy[tid];
  }
}

// ------------- transpose yT [b][768][256] bf16 -> y_bf [2048][768] bf16 ----
__global__ __launch_bounds__(256) void transpose_bf_k(
    const unsigned short* __restrict__ yT, unsigned short* __restrict__ ybf) {
  int b = blockIdx.z;
  int db = blockIdx.y;   // 12 tiles of 64 d
  int lb = blockIdx.x;   // 4 tiles of 64 l
  __shared__ float tile[64][65];
  int tid = threadIdx.x;
  int lx = tid & 63, dq = tid >> 6;
  const unsigned short* src = yT + ((size_t)b * kDI + db * 64) * kL + lb * 64;
  #pragma unroll
  for (int i = 0; i < 16; ++i) {
    int dd = dq * 16 + i;
    unsigned ui = (unsigned)src[(size_t)dd * kL + lx] << 16;
    tile[dd][lx] = __uint_as_float(ui);
  }
  __syncthreads();
  int ly = tid >> 2, dx0 = (tid & 3) * 16;
  unsigned short tmp[16];
  #pragma unroll
  for (int i = 0; i < 16; ++i)
    tmp[i] = (unsigned short)(__float_as_uint(tile[dx0 + i][ly]) >> 16);
  unsigned short* dst =
      ybf + (size_t)(b * kL + lb * 64 + ly) * kDI + db * 64 + dx0;
  *(uint4*)dst = *(const uint4*)tmp;
  *(uint4*)(dst + 8) = *(const uint4*)(tmp + 8);
}

// ---------------- mean pool over L ----------------
__global__ __launch_bounds__(384) void pool_k(
    const float* __restrict__ h, float* __restrict__ pooled) {
  int b = blockIdx.x, d = threadIdx.x;
  float acc = 0.f;
  for (int l = 0; l < kL; ++l) acc += h[(size_t)(b * kL + l) * kDM + d];
  pooled[b * kDM + d] = acc * (1.f / 256.f);
}

// ---------------- head ----------------
__global__ __launch_bounds__(64) void head_k(
    const float* __restrict__ pooled, const float* __restrict__ hw,
    const float* __restrict__ hb, float* __restrict__ out) {
  int b = blockIdx.x >> 2, c = blockIdx.x & 3;
  int lane = threadIdx.x;
  float acc = 0.f;
  for (int dd = lane; dd < kDM; dd += 64)
    acc = fmaf(pooled[b * kDM + dd], hw[c * kDM + dd], acc);
  #pragma unroll
  for (int m = 32; m >= 1; m >>= 1) acc += __shfl_xor(acc, m);
  if (lane == 0) out[b * 4 + c] = acc + hb[c];
}

}  // namespace

extern "C" void kernel_launch(void* const* d_in, const int* in_sizes, int n_in,
                              void* d_out, int out_size, void* d_ws, size_t ws_size,
                              hipStream_t stream) {
  (void)in_sizes; (void)n_in; (void)out_size; (void)ws_size;
  const float* x        = (const float*)d_in[0];
  const float* patch_w  = (const float*)d_in[1];
  const float* patch_b  = (const float*)d_in[2];
  const float* pos      = (const float*)d_in[3];
  const float* ln_g     = (const float*)d_in[4];
  const float* ln_b     = (const float*)d_in[5];
  const float* in_w     = (const float*)d_in[6];
  const float* conv_w   = (const float*)d_in[7];
  const float* conv_b   = (const float*)d_in[8];
  const float* xproj_w  = (const float*)d_in[9];
  const float* dtproj_w = (const float*)d_in[10];
  const float* dtproj_b = (const float*)d_in[11];
  const float* A_log    = (const float*)d_in[12];
  const float* Dskip    = (const float*)d_in[13];
  const float* out_w    = (const float*)d_in[14];
  const float* fn_g     = (const float*)d_in[15];
  const float* fn_b     = (const float*)d_in[16];
  const float* head_w   = (const float*)d_in[17];
  const float* head_b   = (const float*)d_in[18];
  float* out = (float*)d_out;

  float* ws = (float*)d_ws;
  float* tok    = ws; ws += kTok * kDM;       // fp32 residual
  float* xz     = ws; ws += kTok * 2 * kDI;
  float* uT     = ws; ws += kTok * kDI;
  float* sgT    = ws; ws += kTok * kDI;
  float* proj   = ws; ws += kTok * kPROJ;     // [t][56] row-major
  float* pooled = ws; ws += kB * kDM;
  unsigned short* yT_bf = (unsigned short*)ws; ws += kTok * kDI / 2;
  unsigned short* h_bf  = (unsigned short*)ws; ws += kTok * kDM / 2;
  unsigned short* y_bf  = (unsigned short*)ws; ws += kTok * kDI / 2;
  unsigned short* u_bf  = (unsigned short*)ws; ws += kTok * kDI / 2;
  unsigned short* w_bf  = (unsigned short*)ws; ws += (size_t)kNL * kWTOT / 2;
  float* lnout = xz;  // overlay: xz dead after last conv

  // all-layer weight cast (once per call)
  convert_all_k<<<dim3(kWTOT / 4 / 256, kNL), 256, 0, stream>>>(
      in_w, out_w, xproj_w, w_bf);

  // Patch embedding fused: im2col + GEMM + bias + pos
  patch_gemm_k<<<dim3(6, 32), 256, 0, stream>>>(x, patch_w, patch_b, pos, tok);

  for (int layer = 0; layer < kNL; ++layer) {
    const unsigned short* wl = w_bf + (size_t)layer * kWTOT;
    // LN -> bf16 A operand; also zeroes proj for this layer's split-K GEMM
    ln_k<true><<<kTok, kDM, 0, stream>>>(tok, h_bf, ln_g + layer * kDM,
                                         ln_b + layer * kDM, proj);
    // in_proj (MFMA): [2048,384]x[1536,384]^T -> xz fp32
    bgemm_k<128, 0><<<dim3(12, 16, 1), 256, 0, stream>>>(
        h_bf, kDM, wl, kDM, xz, 2 * kDI, 2 * kDI, kDM);
    // depthwise causal conv + SiLU + z-gate -> uT, sgT fp32; u_bf bf16
    conv_tr_k<<<dim3(16, kB), 256, 0, stream>>>(
        xz, conv_w + layer * kDI * 4, conv_b + layer * kDI, uT, sgT, u_bf);
    // x_proj (MFMA, split-K=6, atomic): [2048,768]x[56,768]^T -> proj[t][56]
    bgemm_k<64, 1><<<dim3(1, 16, 6), 256, 0, stream>>>(
        u_bf, kDI, wl + kWIN + kWOUT, kDI, proj, kPROJ, kPROJ, kDI / 6);
    // fused dt_proj + selective scan (4 d/block) -> yT_bf [b][d][l] bf16
    scan4_k<<<dim3(kDI / 4, kB), 256, 0, stream>>>(
        proj, uT, sgT, dtproj_w + (size_t)layer * kDI * kDTR,
        dtproj_b + layer * kDI, A_log + (size_t)layer * kDI * kDS,
        Dskip + layer * kDI, yT_bf);
    // transpose yT_bf -> y_bf [2048,768]
    transpose_bf_k<<<dim3(4, 12, kB), 256, 0, stream>>>(yT_bf, y_bf);
    // out_proj (MFMA, split-K=2, atomic into residual): tok += y x W^T
    bgemm_k<128, 1><<<dim3(3, 16, 2), 256, 0, stream>>>(
        y_bf, kDI, wl + kWIN, kDI, tok, kDM, kDM, kDI / 2);
  }

  ln_k<false><<<kTok, kDM, 0, stream>>>(tok, lnout, fn_g, fn_b, nullptr);
  pool_k<<<kB, kDM, 0, stream>>>(lnout, pooled);
  head_k<<<kB * 4, 64, 0, stream>>>(pooled, head_w, head_b, out);
}

// Round 9
// 1398.668 us; speedup vs baseline: 1.1144x; 1.0263x over previous
//
#include <hip/hip_runtime.h>
#include <math.h>

namespace {

constexpr int kB   = 8;
constexpr int kL   = 256;
constexpr int kTok = 2048;   // B*L
constexpr int kDM  = 384;
constexpr int kDI  = 768;
constexpr int kDS  = 16;
constexpr int kDTR = 24;
constexpr int kPROJ = 56;    // DTR + 2*DS
constexpr int kNL  = 12;

constexpr int kWIN  = 2 * kDI * kDM;   // 589824 in_proj weights/layer
constexpr int kWOUT = kDM * kDI;       // 294912
constexpr int kWX   = kPROJ * kDI;     // 43008
constexpr int kWTOT = kWIN + kWOUT + kWX;  // 927744

typedef float f32x4 __attribute__((ext_vector_type(4)));
typedef short short8 __attribute__((ext_vector_type(8)));

__device__ __forceinline__ float softplus_f(float x) {
  return (x > 20.f) ? x : log1pf(__expf(x));
}
__device__ __forceinline__ float silu_f(float x) {
  return x / (1.f + __expf(-x));
}
__device__ __forceinline__ unsigned short f2bf(float f) {
  union { float f; unsigned u; } v; v.f = f;
  unsigned r = v.u + 0x7FFFu + ((v.u >> 16) & 1u);
  return (unsigned short)(r >> 16);
}

// ------------- patch embed GEMM: tok = im2col(x)·patch_w^T + b + pos -------
__global__ __launch_bounds__(256) void patch_gemm_k(
    const float* __restrict__ x, const float* __restrict__ Bw,
    const float* __restrict__ bias, const float* __restrict__ pos,
    float* __restrict__ C) {
  __shared__ float As[16][68];
  __shared__ float Bs[16][68];
  int tid = threadIdx.x;
  int bm = blockIdx.y * 64;
  int bn = blockIdx.x * 64;
  int lr = tid >> 2;
  int lk = (tid & 3) << 2;
  int tm = (tid >> 4) << 2;
  int tn = (tid & 15) << 2;
  float acc[4][4] = {};
  for (int k0 = 0; k0 < 256; k0 += 16) {
    {
      int token = bm + lr;
      int b = token >> 8, l = token & 255;
      int h = l >> 3, w = l & 7;
      int p = k0 >> 4;
      const float* ap = x + ((size_t)(b * 512) + h * 16 + p) * 128 + w * 16 + lk;
      float4 av = *(const float4*)ap;
      As[lk + 0][lr] = av.x; As[lk + 1][lr] = av.y;
      As[lk + 2][lr] = av.z; As[lk + 3][lr] = av.w;
    }
    {
      const float* bp = Bw + (size_t)(bn + lr) * 256 + k0 + lk;
      float4 bv = *(const float4*)bp;
      Bs[lk + 0][lr] = bv.x; Bs[lk + 1][lr] = bv.y;
      Bs[lk + 2][lr] = bv.z; Bs[lk + 3][lr] = bv.w;
    }
    __syncthreads();
    #pragma unroll
    for (int k = 0; k < 16; ++k) {
      float4 a = *(const float4*)&As[k][tm];
      float4 b = *(const float4*)&Bs[k][tn];
      float av[4] = {a.x, a.y, a.z, a.w};
      float bv[4] = {b.x, b.y, b.z, b.w};
      #pragma unroll
      for (int i = 0; i < 4; ++i)
        #pragma unroll
        for (int j = 0; j < 4; ++j)
          acc[i][j] = fmaf(av[i], bv[j], acc[i][j]);
    }
    __syncthreads();
  }
  #pragma unroll
  for (int i = 0; i < 4; ++i) {
    int row = bm + tm + i;
    #pragma unroll
    for (int j = 0; j < 4; ++j) {
      int col = bn + tn + j;
      C[(size_t)row * kDM + col] =
          acc[i][j] + bias[col] + pos[(size_t)(row & 255) * kDM + col];
    }
  }
}

// ------------- layernorm over DM=384; bf16 out; optionally zero proj -------
template <bool BF16OUT>
__global__ __launch_bounds__(384) void ln_k(
    const float* __restrict__ in, void* __restrict__ outv,
    const float* __restrict__ g, const float* __restrict__ bb,
    float* __restrict__ proj_zero) {
  int t = blockIdx.x, d = threadIdx.x;
  if (proj_zero && d < kPROJ) proj_zero[(size_t)t * kPROJ + d] = 0.f;
  float v = in[(size_t)t * kDM + d];
  float s = v, s2 = v * v;
  #pragma unroll
  for (int m = 32; m >= 1; m >>= 1) {
    s  += __shfl_xor(s, m);
    s2 += __shfl_xor(s2, m);
  }
  __shared__ float ps[6], ps2[6];
  if ((d & 63) == 0) { ps[d >> 6] = s; ps2[d >> 6] = s2; }
  __syncthreads();
  float S = 0.f, S2 = 0.f;
  #pragma unroll
  for (int i = 0; i < 6; ++i) { S += ps[i]; S2 += ps2[i]; }
  float mean = S * (1.f / 384.f);
  float var  = S2 * (1.f / 384.f) - mean * mean;
  float r = rsqrtf(var + 1e-5f);
  float o = (v - mean) * r * g[d] + bb[d];
  if (BF16OUT) ((unsigned short*)outv)[(size_t)t * kDM + d] = f2bf(o);
  else ((float*)outv)[(size_t)t * kDM + d] = o;
}

// ------------- convert ALL layers' GEMM weights fp32 -> bf16 ---------------
__global__ __launch_bounds__(256) void convert_all_k(
    const float* __restrict__ w_in, const float* __restrict__ w_out,
    const float* __restrict__ w_x, unsigned short* __restrict__ dst) {
  int layer = blockIdx.y;
  int i4 = (blockIdx.x * 256 + threadIdx.x) * 4;
  if (i4 >= kWTOT) return;
  const float* src;
  int off;
  if (i4 < kWIN) { src = w_in + (size_t)layer * kWIN; off = i4; }
  else if (i4 < kWIN + kWOUT) { src = w_out + (size_t)layer * kWOUT; off = i4 - kWIN; }
  else { src = w_x + (size_t)layer * kWX; off = i4 - kWIN - kWOUT; }
  float4 v = *(const float4*)(src + off);
  unsigned short o[4] = {f2bf(v.x), f2bf(v.y), f2bf(v.z), f2bf(v.w)};
  *(uint2*)(dst + (size_t)layer * kWTOT + i4) = *(const uint2*)o;
}

// ------------- bf16 MFMA NT GEMM: C[M,N] fp32 = A[M,K]·B[N,K]^T ------------
// EPIL 0: plain store. EPIL 1: atomicAdd (split-K / residual).
template <int BN, int EPIL>
__global__ __launch_bounds__(256) void bgemm_k(
    const unsigned short* __restrict__ A, int lda,
    const unsigned short* __restrict__ B, int ldb,
    float* __restrict__ C, int ldc, int N, int Kc) {
  __shared__ __align__(16) unsigned short As[4][128][8];
  __shared__ __align__(16) unsigned short Bs[4][BN][8];
  int tid = threadIdx.x;
  int bm = blockIdx.y * 128;
  int bn = blockIdx.x * BN;
  int k_begin = blockIdx.z * Kc;
  int wave = tid >> 6, lane = tid & 63;
  int lm = lane & 15, lq = lane >> 4;
  int wm, wn;
  if (BN == 128) { wm = (wave >> 1) * 64; wn = (wave & 1) * 64; }
  else           { wm = wave * 32;        wn = 0; }
  constexpr int MT = (BN == 128) ? 4 : 2;
  f32x4 acc[MT][4] = {};

  for (int kt = 0; kt < Kc; kt += 32) {
    int k0 = k_begin + kt;
    int ar0 = tid & 127, aq0 = tid >> 7;
    int aq1 = aq0 + 2;
    uint4 a0 = *(const uint4*)(A + (size_t)(bm + ar0) * lda + k0 + aq0 * 8);
    uint4 a1 = *(const uint4*)(A + (size_t)(bm + ar0) * lda + k0 + aq1 * 8);
    uint4 b0, b1;
    int br0, bq0, br1 = 0, bq1 = 0;
    if (BN == 128) {
      br0 = tid & 127; bq0 = tid >> 7; br1 = br0; bq1 = bq0 + 2;
      b0 = *(const uint4*)(B + (size_t)(bn + br0) * ldb + k0 + bq0 * 8);
      b1 = *(const uint4*)(B + (size_t)(bn + br1) * ldb + k0 + bq1 * 8);
    } else {
      br0 = tid & 63; bq0 = tid >> 6;
      if (bn + br0 < N)
        b0 = *(const uint4*)(B + (size_t)(bn + br0) * ldb + k0 + bq0 * 8);
      else
        b0 = make_uint4(0u, 0u, 0u, 0u);
    }
    __syncthreads();
    *(uint4*)&As[aq0][ar0][0] = a0;
    *(uint4*)&As[aq1][ar0][0] = a1;
    *(uint4*)&Bs[bq0][br0][0] = b0;
    if (BN == 128) *(uint4*)&Bs[bq1][br1][0] = b1;
    __syncthreads();

    short8 bfrag[4];
    #pragma unroll
    for (int ni = 0; ni < 4; ++ni)
      bfrag[ni] = *(const short8*)&Bs[lq][wn + ni * 16 + lm][0];
    #pragma unroll
    for (int mi = 0; mi < MT; ++mi) {
      short8 afrag = *(const short8*)&As[lq][wm + mi * 16 + lm][0];
      #pragma unroll
      for (int ni = 0; ni < 4; ++ni)
        acc[mi][ni] = __builtin_amdgcn_mfma_f32_16x16x32_bf16(
            afrag, bfrag[ni], acc[mi][ni], 0, 0, 0);
    }
  }

  #pragma unroll
  for (int mi = 0; mi < MT; ++mi) {
    #pragma unroll
    for (int ni = 0; ni < 4; ++ni) {
      int grow0 = bm + wm + mi * 16 + lq * 4;
      int gcol = bn + wn + ni * 16 + lm;
      #pragma unroll
      for (int r = 0; r < 4; ++r) {
        float v = acc[mi][ni][r];
        int grow = grow0 + r;
        if (EPIL == 0) {
          C[(size_t)grow * ldc + gcol] = v;
        } else {
          if (gcol < N) atomicAdd(&C[(size_t)grow * ldc + gcol], v);
        }
      }
    }
  }
}

// ------------- causal depthwise conv (DC=4) + SiLU + z-gate ----------------
__global__ __launch_bounds__(256) void conv_tr_k(
    const float* __restrict__ xz, const float* __restrict__ cw,
    const float* __restrict__ cb, float* __restrict__ uT,
    float* __restrict__ sgT, unsigned short* __restrict__ u_bf) {
  int b = blockIdx.y;
  int l0 = blockIdx.x * 16;
  int tid = threadIdx.x;
  #pragma unroll
  for (int ch = 0; ch < 3; ++ch) {
    int d = ch * 256 + tid;
    float w0 = cw[d * 4], w1 = cw[d * 4 + 1], w2 = cw[d * 4 + 2], w3 = cw[d * 4 + 3];
    float bias = cb[d];
    float v[19];
    #pragma unroll
    for (int j = 0; j < 19; ++j) {
      int l = l0 - 3 + j;
      v[j] = (l >= 0) ? xz[(size_t)(b * kL + l) * (2 * kDI) + d] : 0.f;
    }
    float* up = uT + ((size_t)b * kDI + d) * kL + l0;
    float* sp = sgT + ((size_t)b * kDI + d) * kL + l0;
    #pragma unroll
    for (int i = 0; i < 16; ++i) {
      float acc = bias;
      acc = fmaf(v[i], w0, acc);
      acc = fmaf(v[i + 1], w1, acc);
      acc = fmaf(v[i + 2], w2, acc);
      acc = fmaf(v[i + 3], w3, acc);
      float o = silu_f(acc);
      up[i] = o;
      u_bf[(size_t)(b * kL + l0 + i) * kDI + d] = f2bf(o);
      float zv = xz[(size_t)(b * kL + l0 + i) * (2 * kDI) + kDI + d];
      sp[i] = silu_f(zv);
    }
  }
}

// ------------- register-state selective scan + fused dt_proj ---------------
// One thread per (chunk c, channel d): all 16 SSM states in registers.
// Pass 1: local scan (h0=0) -> chunk summaries (h_end, a-product) to LDS.
// Combine: h0[n] for this chunk via <=15 fma steps over LDS summaries.
// Pass 2: recompute recurrence from true h0, dot with C in-register,
// gate + skip, emit y row-major bf16 (out_proj A operand) directly.
__global__ __launch_bounds__(128) void scanreg_k(
    const float* __restrict__ proj, const float* __restrict__ uT,
    const float* __restrict__ sgT, const float* __restrict__ dtw,
    const float* __restrict__ dtb, const float* __restrict__ A_log,
    const float* __restrict__ Dsk, unsigned short* __restrict__ y_bf) {
  int d0 = blockIdx.x * 8;
  int b = blockIdx.y;
  int tid = threadIdx.x;
  int c = tid >> 3;        // chunk 0..15
  int dsub = tid & 7;
  int d = d0 + dsub;
  __shared__ float sh[16][8][20];   // stride 20 floats: 16B-aligned, no bank clash
  __shared__ float sca[16][8][20];

  float Av[16];
  {
    const float* ap = A_log + (size_t)d * kDS;
    #pragma unroll
    for (int q = 0; q < 4; ++q) {
      float4 v = ((const float4*)ap)[q];
      Av[q * 4 + 0] = -__expf(v.x);
      Av[q * 4 + 1] = -__expf(v.y);
      Av[q * 4 + 2] = -__expf(v.z);
      Av[q * 4 + 3] = -__expf(v.w);
    }
  }
  float bdt = dtb[d];
  float Dv = Dsk[d];

  float u_[16];
  {
    const float* up = uT + ((size_t)b * kDI + d) * kL + c * 16;
    #pragma unroll
    for (int q = 0; q < 4; ++q) {
      float4 v = ((const float4*)up)[q];
      u_[q * 4 + 0] = v.x; u_[q * 4 + 1] = v.y;
      u_[q * 4 + 2] = v.z; u_[q * 4 + 3] = v.w;
    }
  }

  const float* pr = proj + ((size_t)(b * kL) + c * 16) * kPROJ;

  // fused dt_proj: delta for this thread's 16 tokens
  float dt_[16];
  {
    float wdt[24];
    const float* wp = dtw + (size_t)d * kDTR;
    #pragma unroll
    for (int q = 0; q < 6; ++q) {
      float4 v = ((const float4*)wp)[q];
      wdt[q * 4 + 0] = v.x; wdt[q * 4 + 1] = v.y;
      wdt[q * 4 + 2] = v.z; wdt[q * 4 + 3] = v.w;
    }
    #pragma unroll
    for (int i = 0; i < 16; ++i) {
      const float* p = pr + (size_t)i * kPROJ;
      float acc = bdt;
      #pragma unroll
      for (int q = 0; q < 6; ++q) {
        float4 v = ((const float4*)p)[q];
        acc = fmaf(v.x, wdt[q * 4 + 0], acc);
        acc = fmaf(v.y, wdt[q * 4 + 1], acc);
        acc = fmaf(v.z, wdt[q * 4 + 2], acc);
        acc = fmaf(v.w, wdt[q * 4 + 3], acc);
      }
      dt_[i] = softplus_f(acc);
    }
  }

  // pass 1: local chunk scan, all n in registers
  float h[16], ca[16];
  #pragma unroll
  for (int n = 0; n < 16; ++n) { h[n] = 0.f; ca[n] = 1.f; }
  #pragma unroll
  for (int i = 0; i < 16; ++i) {
    float dl = dt_[i];
    float du = dl * u_[i];
    const float* p = pr + (size_t)i * kPROJ + 24;
    float Bv[16];
    #pragma unroll
    for (int q = 0; q < 4; ++q) {
      float4 v = ((const float4*)p)[q];
      Bv[q * 4 + 0] = v.x; Bv[q * 4 + 1] = v.y;
      Bv[q * 4 + 2] = v.z; Bv[q * 4 + 3] = v.w;
    }
    #pragma unroll
    for (int n = 0; n < 16; ++n) {
      float a = __expf(dl * Av[n]);
      h[n] = fmaf(a, h[n], du * Bv[n]);
      ca[n] *= a;
    }
  }
  #pragma unroll
  for (int q = 0; q < 4; ++q) {
    *(float4*)&sh[c][dsub][q * 4] =
        make_float4(h[q * 4], h[q * 4 + 1], h[q * 4 + 2], h[q * 4 + 3]);
    *(float4*)&sca[c][dsub][q * 4] =
        make_float4(ca[q * 4], ca[q * 4 + 1], ca[q * 4 + 2], ca[q * 4 + 3]);
  }
  __syncthreads();

  // chunk-prefix combine
  float h0[16];
  #pragma unroll
  for (int n = 0; n < 16; ++n) h0[n] = 0.f;
  for (int j = 0; j < c; ++j) {
    #pragma unroll
    for (int q = 0; q < 4; ++q) {
      float4 hh = *(const float4*)&sh[j][dsub][q * 4];
      float4 aa = *(const float4*)&sca[j][dsub][q * 4];
      h0[q * 4 + 0] = fmaf(aa.x, h0[q * 4 + 0], hh.x);
      h0[q * 4 + 1] = fmaf(aa.y, h0[q * 4 + 1], hh.y);
      h0[q * 4 + 2] = fmaf(aa.z, h0[q * 4 + 2], hh.z);
      h0[q * 4 + 3] = fmaf(aa.w, h0[q * 4 + 3], hh.w);
    }
  }

  float sg_[16];
  {
    const float* sp = sgT + ((size_t)b * kDI + d) * kL + c * 16;
    #pragma unroll
    for (int q = 0; q < 4; ++q) {
      float4 v = ((const float4*)sp)[q];
      sg_[q * 4 + 0] = v.x; sg_[q * 4 + 1] = v.y;
      sg_[q * 4 + 2] = v.z; sg_[q * 4 + 3] = v.w;
    }
  }

  // pass 2: true scan from h0; emit y row-major bf16
  unsigned short* yp = y_bf + (size_t)(b * kL + c * 16) * kDI + d;
  #pragma unroll
  for (int i = 0; i < 16; ++i) {
    float dl = dt_[i];
    float du = dl * u_[i];
    const float* p = pr + (size_t)i * kPROJ + 24;
    float Bv[16], Cv[16];
    #pragma unroll
    for (int q = 0; q < 4; ++q) {
      float4 v = ((const float4*)p)[q];
      float4 w = ((const float4*)p)[q + 4];
      Bv[q * 4 + 0] = v.x; Bv[q * 4 + 1] = v.y;
      Bv[q * 4 + 2] = v.z; Bv[q * 4 + 3] = v.w;
      Cv[q * 4 + 0] = w.x; Cv[q * 4 + 1] = w.y;
      Cv[q * 4 + 2] = w.z; Cv[q * 4 + 3] = w.w;
    }
    float yv = 0.f;
    #pragma unroll
    for (int n = 0; n < 16; ++n) {
      float a = __expf(dl * Av[n]);
      h0[n] = fmaf(a, h0[n], du * Bv[n]);
      yv = fmaf(h0[n], Cv[n], yv);
    }
    yp[(size_t)i * kDI] = f2bf((yv + u_[i] * Dv) * sg_[i]);
  }
}

// ---------------- mean pool over L ----------------
__global__ __launch_bounds__(384) void pool_k(
    const float* __restrict__ h, float* __restrict__ pooled) {
  int b = blockIdx.x, d = threadIdx.x;
  float acc = 0.f;
  for (int l = 0; l < kL; ++l) acc += h[(size_t)(b * kL + l) * kDM + d];
  pooled[b * kDM + d] = acc * (1.f / 256.f);
}

// ---------------- head ----------------
__global__ __launch_bounds__(64) void head_k(
    const float* __restrict__ pooled, const float* __restrict__ hw,
    const float* __restrict__ hb, float* __restrict__ out) {
  int b = blockIdx.x >> 2, c = blockIdx.x & 3;
  int lane = threadIdx.x;
  float acc = 0.f;
  for (int dd = lane; dd < kDM; dd += 64)
    acc = fmaf(pooled[b * kDM + dd], hw[c * kDM + dd], acc);
  #pragma unroll
  for (int m = 32; m >= 1; m >>= 1) acc += __shfl_xor(acc, m);
  if (lane == 0) out[b * 4 + c] = acc + hb[c];
}

}  // namespace

extern "C" void kernel_launch(void* const* d_in, const int* in_sizes, int n_in,
                              void* d_out, int out_size, void* d_ws, size_t ws_size,
                              hipStream_t stream) {
  (void)in_sizes; (void)n_in; (void)out_size; (void)ws_size;
  const float* x        = (const float*)d_in[0];
  const float* patch_w  = (const float*)d_in[1];
  const float* patch_b  = (const float*)d_in[2];
  const float* pos      = (const float*)d_in[3];
  const float* ln_g     = (const float*)d_in[4];
  const float* ln_b     = (const float*)d_in[5];
  const float* in_w     = (const float*)d_in[6];
  const float* conv_w   = (const float*)d_in[7];
  const float* conv_b   = (const float*)d_in[8];
  const float* xproj_w  = (const float*)d_in[9];
  const float* dtproj_w = (const float*)d_in[10];
  const float* dtproj_b = (const float*)d_in[11];
  const float* A_log    = (const float*)d_in[12];
  const float* Dskip    = (const float*)d_in[13];
  const float* out_w    = (const float*)d_in[14];
  const float* fn_g     = (const float*)d_in[15];
  const float* fn_b     = (const float*)d_in[16];
  const float* head_w   = (const float*)d_in[17];
  const float* head_b   = (const float*)d_in[18];
  float* out = (float*)d_out;

  float* ws = (float*)d_ws;
  float* tok    = ws; ws += kTok * kDM;       // fp32 residual
  float* xz     = ws; ws += kTok * 2 * kDI;
  float* uT     = ws; ws += kTok * kDI;
  float* sgT    = ws; ws += kTok * kDI;
  float* proj   = ws; ws += kTok * kPROJ;     // [t][56] row-major
  float* pooled = ws; ws += kB * kDM;
  unsigned short* h_bf = (unsigned short*)ws; ws += kTok * kDM / 2;
  unsigned short* y_bf = (unsigned short*)ws; ws += kTok * kDI / 2;
  unsigned short* u_bf = (unsigned short*)ws; ws += kTok * kDI / 2;
  unsigned short* w_bf = (unsigned short*)ws; ws += (size_t)kNL * kWTOT / 2;
  float* lnout = xz;  // overlay: xz dead after last conv

  // all-layer weight cast (once per call)
  convert_all_k<<<dim3(kWTOT / 4 / 256, kNL), 256, 0, stream>>>(
      in_w, out_w, xproj_w, w_bf);

  // Patch embedding fused: im2col + GEMM + bias + pos
  patch_gemm_k<<<dim3(6, 32), 256, 0, stream>>>(x, patch_w, patch_b, pos, tok);

  for (int layer = 0; layer < kNL; ++layer) {
    const unsigned short* wl = w_bf + (size_t)layer * kWTOT;
    // LN -> bf16 A operand; also zeroes proj for this layer's split-K GEMM
    ln_k<true><<<kTok, kDM, 0, stream>>>(tok, h_bf, ln_g + layer * kDM,
                                         ln_b + layer * kDM, proj);
    // in_proj (MFMA, BN=64 for 384 blocks): [2048,384]x[1536,384]^T -> xz
    bgemm_k<64, 0><<<dim3(24, 16, 1), 256, 0, stream>>>(
        h_bf, kDM, wl, kDM, xz, 2 * kDI, 2 * kDI, kDM);
    // depthwise causal conv + SiLU + z-gate -> uT, sgT fp32; u_bf bf16
    conv_tr_k<<<dim3(16, kB), 256, 0, stream>>>(
        xz, conv_w + layer * kDI * 4, conv_b + layer * kDI, uT, sgT, u_bf);
    // x_proj (MFMA, split-K=6, atomic): [2048,768]x[56,768]^T -> proj[t][56]
    bgemm_k<64, 1><<<dim3(1, 16, 6), 256, 0, stream>>>(
        u_bf, kDI, wl + kWIN + kWOUT, kDI, proj, kPROJ, kPROJ, kDI / 6);
    // register-state scan + fused dt_proj -> y_bf[token][768] bf16 (direct)
    scanreg_k<<<dim3(kDI / 8, kB), 128, 0, stream>>>(
        proj, uT, sgT, dtproj_w + (size_t)layer * kDI * kDTR,
        dtproj_b + layer * kDI, A_log + (size_t)layer * kDI * kDS,
        Dskip + layer * kDI, y_bf);
    // out_proj (MFMA, split-K=2, atomic into residual): tok += y x W^T
    bgemm_k<128, 1><<<dim3(3, 16, 2), 256, 0, stream>>>(
        y_bf, kDI, wl + kWIN, kDI, tok, kDM, kDM, kDI / 2);
  }

  ln_k<false><<<kTok, kDM, 0, stream>>>(tok, lnout, fn_g, fn_b, nullptr);
  pool_k<<<kB, kDM, 0, stream>>>(lnout, pooled);
  head_k<<<kB * 4, 64, 0, stream>>>(pooled, head_w, head_b, out);
}

// Round 10
// 1344.359 us; speedup vs baseline: 1.1595x; 1.0404x over previous
//
#include <hip/hip_runtime.h>
#include <math.h>

namespace {

constexpr int kB   = 8;
constexpr int kL   = 256;
constexpr int kTok = 2048;   // B*L
constexpr int kDM  = 384;
constexpr int kDI  = 768;
constexpr int kDS  = 16;
constexpr int kDTR = 24;
constexpr int kPROJ = 56;    // DTR + 2*DS
constexpr int kNL  = 12;

constexpr int kWIN  = 2 * kDI * kDM;   // 589824 in_proj weights/layer
constexpr int kWOUT = kDM * kDI;       // 294912
constexpr int kWX   = kPROJ * kDI;     // 43008
constexpr int kWTOT = kWIN + kWOUT + kWX;  // 927744

typedef float f32x4 __attribute__((ext_vector_type(4)));
typedef short short8 __attribute__((ext_vector_type(8)));

__device__ __forceinline__ float softplus_f(float x) {
  return (x > 20.f) ? x : log1pf(__expf(x));
}
__device__ __forceinline__ float silu_f(float x) {
  return x / (1.f + __expf(-x));
}
__device__ __forceinline__ unsigned short f2bf(float f) {
  union { float f; unsigned u; } v; v.f = f;
  unsigned r = v.u + 0x7FFFu + ((v.u >> 16) & 1u);
  return (unsigned short)(r >> 16);
}
__device__ __forceinline__ float bf2f(unsigned short u) {
  return __uint_as_float((unsigned)u << 16);
}

// ------------- patch embed GEMM: tok = im2col(x)·patch_w^T + b + pos -------
__global__ __launch_bounds__(256) void patch_gemm_k(
    const float* __restrict__ x, const float* __restrict__ Bw,
    const float* __restrict__ bias, const float* __restrict__ pos,
    float* __restrict__ C) {
  __shared__ float As[16][68];
  __shared__ float Bs[16][68];
  int tid = threadIdx.x;
  int bm = blockIdx.y * 64;
  int bn = blockIdx.x * 64;
  int lr = tid >> 2;
  int lk = (tid & 3) << 2;
  int tm = (tid >> 4) << 2;
  int tn = (tid & 15) << 2;
  float acc[4][4] = {};
  for (int k0 = 0; k0 < 256; k0 += 16) {
    {
      int token = bm + lr;
      int b = token >> 8, l = token & 255;
      int h = l >> 3, w = l & 7;
      int p = k0 >> 4;
      const float* ap = x + ((size_t)(b * 512) + h * 16 + p) * 128 + w * 16 + lk;
      float4 av = *(const float4*)ap;
      As[lk + 0][lr] = av.x; As[lk + 1][lr] = av.y;
      As[lk + 2][lr] = av.z; As[lk + 3][lr] = av.w;
    }
    {
      const float* bp = Bw + (size_t)(bn + lr) * 256 + k0 + lk;
      float4 bv = *(const float4*)bp;
      Bs[lk + 0][lr] = bv.x; Bs[lk + 1][lr] = bv.y;
      Bs[lk + 2][lr] = bv.z; Bs[lk + 3][lr] = bv.w;
    }
    __syncthreads();
    #pragma unroll
    for (int k = 0; k < 16; ++k) {
      float4 a = *(const float4*)&As[k][tm];
      float4 b = *(const float4*)&Bs[k][tn];
      float av[4] = {a.x, a.y, a.z, a.w};
      float bv[4] = {b.x, b.y, b.z, b.w};
      #pragma unroll
      for (int i = 0; i < 4; ++i)
        #pragma unroll
        for (int j = 0; j < 4; ++j)
          acc[i][j] = fmaf(av[i], bv[j], acc[i][j]);
    }
    __syncthreads();
  }
  #pragma unroll
  for (int i = 0; i < 4; ++i) {
    int row = bm + tm + i;
    #pragma unroll
    for (int j = 0; j < 4; ++j) {
      int col = bn + tn + j;
      C[(size_t)row * kDM + col] =
          acc[i][j] + bias[col] + pos[(size_t)(row & 255) * kDM + col];
    }
  }
}

// ------------- layernorm over DM=384; bf16 out; optionally zero proj -------
template <bool BF16OUT>
__global__ __launch_bounds__(384) void ln_k(
    const float* __restrict__ in, void* __restrict__ outv,
    const float* __restrict__ g, const float* __restrict__ bb,
    float* __restrict__ proj_zero) {
  int t = blockIdx.x, d = threadIdx.x;
  if (proj_zero && d < kPROJ) proj_zero[(size_t)t * kPROJ + d] = 0.f;
  float v = in[(size_t)t * kDM + d];
  float s = v, s2 = v * v;
  #pragma unroll
  for (int m = 32; m >= 1; m >>= 1) {
    s  += __shfl_xor(s, m);
    s2 += __shfl_xor(s2, m);
  }
  __shared__ float ps[6], ps2[6];
  if ((d & 63) == 0) { ps[d >> 6] = s; ps2[d >> 6] = s2; }
  __syncthreads();
  float S = 0.f, S2 = 0.f;
  #pragma unroll
  for (int i = 0; i < 6; ++i) { S += ps[i]; S2 += ps2[i]; }
  float mean = S * (1.f / 384.f);
  float var  = S2 * (1.f / 384.f) - mean * mean;
  float r = rsqrtf(var + 1e-5f);
  float o = (v - mean) * r * g[d] + bb[d];
  if (BF16OUT) ((unsigned short*)outv)[(size_t)t * kDM + d] = f2bf(o);
  else ((float*)outv)[(size_t)t * kDM + d] = o;
}

// ------------- convert ALL layers' GEMM weights fp32 -> bf16 ---------------
__global__ __launch_bounds__(256) void convert_all_k(
    const float* __restrict__ w_in, const float* __restrict__ w_out,
    const float* __restrict__ w_x, unsigned short* __restrict__ dst) {
  int layer = blockIdx.y;
  int i4 = (blockIdx.x * 256 + threadIdx.x) * 4;
  if (i4 >= kWTOT) return;
  const float* src;
  int off;
  if (i4 < kWIN) { src = w_in + (size_t)layer * kWIN; off = i4; }
  else if (i4 < kWIN + kWOUT) { src = w_out + (size_t)layer * kWOUT; off = i4 - kWIN; }
  else { src = w_x + (size_t)layer * kWX; off = i4 - kWIN - kWOUT; }
  float4 v = *(const float4*)(src + off);
  unsigned short o[4] = {f2bf(v.x), f2bf(v.y), f2bf(v.z), f2bf(v.w)};
  *(uint2*)(dst + (size_t)layer * kWTOT + i4) = *(const uint2*)o;
}

// ------------- bf16 MFMA NT GEMM: C[M,N] = A[M,K]·B[N,K]^T -----------------
// EPIL 0: fp32 store. EPIL 1: fp32 atomicAdd. EPIL 3: bf16 store.
template <int BN, int EPIL>
__global__ __launch_bounds__(256) void bgemm_k(
    const unsigned short* __restrict__ A, int lda,
    const unsigned short* __restrict__ B, int ldb,
    void* __restrict__ Cv, int ldc, int N, int Kc) {
  __shared__ __align__(16) unsigned short As[4][128][8];
  __shared__ __align__(16) unsigned short Bs[4][BN][8];
  int tid = threadIdx.x;
  int bm = blockIdx.y * 128;
  int bn = blockIdx.x * BN;
  int k_begin = blockIdx.z * Kc;
  int wave = tid >> 6, lane = tid & 63;
  int lm = lane & 15, lq = lane >> 4;
  int wm, wn;
  if (BN == 128) { wm = (wave >> 1) * 64; wn = (wave & 1) * 64; }
  else           { wm = wave * 32;        wn = 0; }
  constexpr int MT = (BN == 128) ? 4 : 2;
  f32x4 acc[MT][4] = {};

  for (int kt = 0; kt < Kc; kt += 32) {
    int k0 = k_begin + kt;
    int ar0 = tid & 127, aq0 = tid >> 7;
    int aq1 = aq0 + 2;
    uint4 a0 = *(const uint4*)(A + (size_t)(bm + ar0) * lda + k0 + aq0 * 8);
    uint4 a1 = *(const uint4*)(A + (size_t)(bm + ar0) * lda + k0 + aq1 * 8);
    uint4 b0, b1;
    int br0, bq0, br1 = 0, bq1 = 0;
    if (BN == 128) {
      br0 = tid & 127; bq0 = tid >> 7; br1 = br0; bq1 = bq0 + 2;
      b0 = *(const uint4*)(B + (size_t)(bn + br0) * ldb + k0 + bq0 * 8);
      b1 = *(const uint4*)(B + (size_t)(bn + br1) * ldb + k0 + bq1 * 8);
    } else {
      br0 = tid & 63; bq0 = tid >> 6;
      if (bn + br0 < N)
        b0 = *(const uint4*)(B + (size_t)(bn + br0) * ldb + k0 + bq0 * 8);
      else
        b0 = make_uint4(0u, 0u, 0u, 0u);
    }
    __syncthreads();
    *(uint4*)&As[aq0][ar0][0] = a0;
    *(uint4*)&As[aq1][ar0][0] = a1;
    *(uint4*)&Bs[bq0][br0][0] = b0;
    if (BN == 128) *(uint4*)&Bs[bq1][br1][0] = b1;
    __syncthreads();

    short8 bfrag[4];
    #pragma unroll
    for (int ni = 0; ni < 4; ++ni)
      bfrag[ni] = *(const short8*)&Bs[lq][wn + ni * 16 + lm][0];
    #pragma unroll
    for (int mi = 0; mi < MT; ++mi) {
      short8 afrag = *(const short8*)&As[lq][wm + mi * 16 + lm][0];
      #pragma unroll
      for (int ni = 0; ni < 4; ++ni)
        acc[mi][ni] = __builtin_amdgcn_mfma_f32_16x16x32_bf16(
            afrag, bfrag[ni], acc[mi][ni], 0, 0, 0);
    }
  }

  #pragma unroll
  for (int mi = 0; mi < MT; ++mi) {
    #pragma unroll
    for (int ni = 0; ni < 4; ++ni) {
      int grow0 = bm + wm + mi * 16 + lq * 4;
      int gcol = bn + wn + ni * 16 + lm;
      #pragma unroll
      for (int r = 0; r < 4; ++r) {
        float v = acc[mi][ni][r];
        int grow = grow0 + r;
        if (EPIL == 0) {
          ((float*)Cv)[(size_t)grow * ldc + gcol] = v;
        } else if (EPIL == 1) {
          if (gcol < N) atomicAdd(&((float*)Cv)[(size_t)grow * ldc + gcol], v);
        } else {
          ((unsigned short*)Cv)[(size_t)grow * ldc + gcol] = f2bf(v);
        }
      }
    }
  }
}

// ------------- causal depthwise conv (DC=4) + SiLU + z-gate ----------------
// xz is bf16 [t][1536]; writes uT fp32 [b][d][l], sgT bf16 [b][d][l],
// u_bf bf16 [t][768]
__global__ __launch_bounds__(256) void conv_tr_k(
    const unsigned short* __restrict__ xz, const float* __restrict__ cw,
    const float* __restrict__ cb, float* __restrict__ uT,
    unsigned short* __restrict__ sgT, unsigned short* __restrict__ u_bf) {
  int b = blockIdx.y;
  int l0 = blockIdx.x * 16;
  int tid = threadIdx.x;
  #pragma unroll
  for (int ch = 0; ch < 3; ++ch) {
    int d = ch * 256 + tid;
    float w0 = cw[d * 4], w1 = cw[d * 4 + 1], w2 = cw[d * 4 + 2], w3 = cw[d * 4 + 3];
    float bias = cb[d];
    float v[19];
    #pragma unroll
    for (int j = 0; j < 19; ++j) {
      int l = l0 - 3 + j;
      v[j] = (l >= 0) ? bf2f(xz[(size_t)(b * kL + l) * (2 * kDI) + d]) : 0.f;
    }
    float* up = uT + ((size_t)b * kDI + d) * kL + l0;
    unsigned short* sp = sgT + ((size_t)b * kDI + d) * kL + l0;
    #pragma unroll
    for (int i = 0; i < 16; ++i) {
      float acc = bias;
      acc = fmaf(v[i], w0, acc);
      acc = fmaf(v[i + 1], w1, acc);
      acc = fmaf(v[i + 2], w2, acc);
      acc = fmaf(v[i + 3], w3, acc);
      float o = silu_f(acc);
      up[i] = o;
      u_bf[(size_t)(b * kL + l0 + i) * kDI + d] = f2bf(o);
      float zv = bf2f(xz[(size_t)(b * kL + l0 + i) * (2 * kDI) + kDI + d]);
      sp[i] = f2bf(silu_f(zv));
    }
  }
}

// ------------- split-state register scan + fused dt_proj -------------------
// thread = (chunk c[16], state-half nh[2], dsub[8]); 8 SSM states/thread in
// registers. dt for my 8 tokens computed, other 8 exchanged via shfl_xor(,8).
// n-reduction = 8 in-register FMAs + one shfl_xor(yv,8). 2 barriers total.
__global__ __launch_bounds__(256) void scansplit_k(
    const float* __restrict__ proj, const float* __restrict__ uT,
    const unsigned short* __restrict__ sgT, const float* __restrict__ dtw,
    const float* __restrict__ dtb, const float* __restrict__ A_log,
    const float* __restrict__ Dsk, unsigned short* __restrict__ y_bf) {
  int d0 = blockIdx.x * 8;
  int b = blockIdx.y;
  int tid = threadIdx.x;
  int dsub = tid & 7;
  int nh = (tid >> 3) & 1;
  int c = tid >> 4;
  int d = d0 + dsub;
  __shared__ float sh[16][16][9];
  __shared__ float sca[16][16][9];

  float Av[8];
  {
    const float* ap = A_log + (size_t)d * kDS + nh * 8;
    #pragma unroll
    for (int q = 0; q < 2; ++q) {
      float4 v = ((const float4*)ap)[q];
      Av[q * 4 + 0] = -__expf(v.x);
      Av[q * 4 + 1] = -__expf(v.y);
      Av[q * 4 + 2] = -__expf(v.z);
      Av[q * 4 + 3] = -__expf(v.w);
    }
  }
  float bdt = dtb[d];
  float Dv = Dsk[d];

  const float* pr = proj + ((size_t)(b * kL) + c * 16) * kPROJ;

  // dt: my 8 tokens (l = c*16 + nh*8 + i), partner's 8 via shuffle
  float dtlo[8], dthi[8];
  {
    float wdt[24];
    const float* wp = dtw + (size_t)d * kDTR;
    #pragma unroll
    for (int q = 0; q < 6; ++q) {
      float4 v = ((const float4*)wp)[q];
      wdt[q * 4 + 0] = v.x; wdt[q * 4 + 1] = v.y;
      wdt[q * 4 + 2] = v.z; wdt[q * 4 + 3] = v.w;
    }
    const float* prm = pr + (size_t)(nh * 8) * kPROJ;
    float mine[8];
    #pragma unroll
    for (int i = 0; i < 8; ++i) {
      const float* p = prm + (size_t)i * kPROJ;
      float acc = bdt;
      #pragma unroll
      for (int q = 0; q < 6; ++q) {
        float4 v = ((const float4*)p)[q];
        acc = fmaf(v.x, wdt[q * 4 + 0], acc);
        acc = fmaf(v.y, wdt[q * 4 + 1], acc);
        acc = fmaf(v.z, wdt[q * 4 + 2], acc);
        acc = fmaf(v.w, wdt[q * 4 + 3], acc);
      }
      mine[i] = softplus_f(acc);
    }
    #pragma unroll
    for (int i = 0; i < 8; ++i) {
      float other = __shfl_xor(mine[i], 8);
      dtlo[i] = nh ? other : mine[i];
      dthi[i] = nh ? mine[i] : other;
    }
  }

  float u_[16];
  {
    const float* up = uT + ((size_t)b * kDI + d) * kL + c * 16;
    #pragma unroll
    for (int q = 0; q < 4; ++q) {
      float4 v = ((const float4*)up)[q];
      u_[q * 4 + 0] = v.x; u_[q * 4 + 1] = v.y;
      u_[q * 4 + 2] = v.z; u_[q * 4 + 3] = v.w;
    }
  }

  // pass 1: local chunk scan over my 8 states
  float h[8], ca[8];
  #pragma unroll
  for (int n = 0; n < 8; ++n) { h[n] = 0.f; ca[n] = 1.f; }
  #pragma unroll
  for (int i = 0; i < 16; ++i) {
    float dl = (i < 8) ? dtlo[i] : dthi[i - 8];
    float du = dl * u_[i];
    const float* p = pr + (size_t)i * kPROJ + 24 + nh * 8;
    float4 b0 = ((const float4*)p)[0];
    float4 b1 = ((const float4*)p)[1];
    float Bv[8] = {b0.x, b0.y, b0.z, b0.w, b1.x, b1.y, b1.z, b1.w};
    #pragma unroll
    for (int n = 0; n < 8; ++n) {
      float a = __expf(dl * Av[n]);
      h[n] = fmaf(a, h[n], du * Bv[n]);
      ca[n] *= a;
    }
  }
  {
    int nrow = nh * 8;
    #pragma unroll
    for (int q = 0; q < 8; ++q) {
      sh[c][nrow + q][dsub] = h[q];
      sca[c][nrow + q][dsub] = ca[q];
    }
  }
  __syncthreads();

  // chunk-prefix combine
  float h0[8];
  #pragma unroll
  for (int n = 0; n < 8; ++n) h0[n] = 0.f;
  {
    int nrow = nh * 8;
    for (int j = 0; j < c; ++j) {
      #pragma unroll
      for (int q = 0; q < 8; ++q)
        h0[q] = fmaf(sca[j][nrow + q][dsub], h0[q], sh[j][nrow + q][dsub]);
    }
  }

  float sg_[16];
  {
    const unsigned short* sp = sgT + ((size_t)b * kDI + d) * kL + c * 16;
    #pragma unroll
    for (int i = 0; i < 16; ++i) sg_[i] = bf2f(sp[i]);
  }

  // pass 2: true scan from h0; partial y over my 8 states; 1 shuffle; store
  unsigned short* yp = y_bf + (size_t)(b * kL + c * 16) * kDI + d;
  #pragma unroll
  for (int i = 0; i < 16; ++i) {
    float dl = (i < 8) ? dtlo[i] : dthi[i - 8];
    float du = dl * u_[i];
    const float* p = pr + (size_t)i * kPROJ + 24 + nh * 8;
    float4 b0 = ((const float4*)p)[0];
    float4 b1 = ((const float4*)p)[1];
    float4 c0 = ((const float4*)(p + 16))[0];
    float4 c1 = ((const float4*)(p + 16))[1];
    float Bv[8] = {b0.x, b0.y, b0.z, b0.w, b1.x, b1.y, b1.z, b1.w};
    float Cv[8] = {c0.x, c0.y, c0.z, c0.w, c1.x, c1.y, c1.z, c1.w};
    float yv = 0.f;
    #pragma unroll
    for (int n = 0; n < 8; ++n) {
      float a = __expf(dl * Av[n]);
      h0[n] = fmaf(a, h0[n], du * Bv[n]);
      yv = fmaf(h0[n], Cv[n], yv);
    }
    yv += __shfl_xor(yv, 8);
    if (nh == 0) yp[(size_t)i * kDI] = f2bf((yv + u_[i] * Dv) * sg_[i]);
  }
}

// ---------------- mean pool over L ----------------
__global__ __launch_bounds__(384) void pool_k(
    const float* __restrict__ h, float* __restrict__ pooled) {
  int b = blockIdx.x, d = threadIdx.x;
  float acc = 0.f;
  for (int l = 0; l < kL; ++l) acc += h[(size_t)(b * kL + l) * kDM + d];
  pooled[b * kDM + d] = acc * (1.f / 256.f);
}

// ---------------- head ----------------
__global__ __launch_bounds__(64) void head_k(
    const float* __restrict__ pooled, const float* __restrict__ hw,
    const float* __restrict__ hb, float* __restrict__ out) {
  int b = blockIdx.x >> 2, c = blockIdx.x & 3;
  int lane = threadIdx.x;
  float acc = 0.f;
  for (int dd = lane; dd < kDM; dd += 64)
    acc = fmaf(pooled[b * kDM + dd], hw[c * kDM + dd], acc);
  #pragma unroll
  for (int m = 32; m >= 1; m >>= 1) acc += __shfl_xor(acc, m);
  if (lane == 0) out[b * 4 + c] = acc + hb[c];
}

}  // namespace

extern "C" void kernel_launch(void* const* d_in, const int* in_sizes, int n_in,
                              void* d_out, int out_size, void* d_ws, size_t ws_size,
                              hipStream_t stream) {
  (void)in_sizes; (void)n_in; (void)out_size; (void)ws_size;
  const float* x        = (const float*)d_in[0];
  const float* patch_w  = (const float*)d_in[1];
  const float* patch_b  = (const float*)d_in[2];
  const float* pos      = (const float*)d_in[3];
  const float* ln_g     = (const float*)d_in[4];
  const float* ln_b     = (const float*)d_in[5];
  const float* in_w     = (const float*)d_in[6];
  const float* conv_w   = (const float*)d_in[7];
  const float* conv_b   = (const float*)d_in[8];
  const float* xproj_w  = (const float*)d_in[9];
  const float* dtproj_w = (const float*)d_in[10];
  const float* dtproj_b = (const float*)d_in[11];
  const float* A_log    = (const float*)d_in[12];
  const float* Dskip    = (const float*)d_in[13];
  const float* out_w    = (const float*)d_in[14];
  const float* fn_g     = (const float*)d_in[15];
  const float* fn_b     = (const float*)d_in[16];
  const float* head_w   = (const float*)d_in[17];
  const float* head_b   = (const float*)d_in[18];
  float* out = (float*)d_out;

  float* ws = (float*)d_ws;
  float* tok    = ws; ws += kTok * kDM;       // fp32 residual
  float* uT     = ws; ws += kTok * kDI;
  float* proj   = ws; ws += kTok * kPROJ;     // [t][56] row-major
  float* pooled = ws; ws += kB * kDM;
  unsigned short* xz_bf = (unsigned short*)ws; ws += kTok * 2 * kDI / 2;
  unsigned short* sgT   = (unsigned short*)ws; ws += kTok * kDI / 2;
  unsigned short* h_bf  = (unsigned short*)ws; ws += kTok * kDM / 2;
  unsigned short* y_bf  = (unsigned short*)ws; ws += kTok * kDI / 2;
  unsigned short* u_bf  = (unsigned short*)ws; ws += kTok * kDI / 2;
  unsigned short* w_bf  = (unsigned short*)ws; ws += (size_t)kNL * kWTOT / 2;
  float* lnout = uT;  // overlay: uT dead after last scan

  // all-layer weight cast (once per call)
  convert_all_k<<<dim3(kWTOT / 4 / 256, kNL), 256, 0, stream>>>(
      in_w, out_w, xproj_w, w_bf);

  // Patch embedding fused: im2col + GEMM + bias + pos
  patch_gemm_k<<<dim3(6, 32), 256, 0, stream>>>(x, patch_w, patch_b, pos, tok);

  for (int layer = 0; layer < kNL; ++layer) {
    const unsigned short* wl = w_bf + (size_t)layer * kWTOT;
    // LN -> bf16 A operand; also zeroes proj for this layer's split-K GEMM
    ln_k<true><<<kTok, kDM, 0, stream>>>(tok, h_bf, ln_g + layer * kDM,
                                         ln_b + layer * kDM, proj);
    // in_proj (MFMA, bf16 out): [2048,384]x[1536,384]^T -> xz_bf
    bgemm_k<64, 3><<<dim3(24, 16, 1), 256, 0, stream>>>(
        h_bf, kDM, wl, kDM, xz_bf, 2 * kDI, 2 * kDI, kDM);
    // depthwise causal conv + SiLU + z-gate -> uT fp32, sgT bf16, u_bf bf16
    conv_tr_k<<<dim3(16, kB), 256, 0, stream>>>(
        xz_bf, conv_w + layer * kDI * 4, conv_b + layer * kDI, uT, sgT, u_bf);
    // x_proj (MFMA, split-K=6, atomic): [2048,768]x[56,768]^T -> proj[t][56]
    bgemm_k<64, 1><<<dim3(1, 16, 6), 256, 0, stream>>>(
        u_bf, kDI, wl + kWIN + kWOUT, kDI, proj, kPROJ, kPROJ, kDI / 6);
    // split-state register scan + fused dt_proj -> y_bf[token][768] bf16
    scansplit_k<<<dim3(kDI / 8, kB), 256, 0, stream>>>(
        proj, uT, sgT, dtproj_w + (size_t)layer * kDI * kDTR,
        dtproj_b + layer * kDI, A_log + (size_t)layer * kDI * kDS,
        Dskip + layer * kDI, y_bf);
    // out_proj (MFMA, split-K=2, atomic into residual): tok += y x W^T
    bgemm_k<128, 1><<<dim3(3, 16, 2), 256, 0, stream>>>(
        y_bf, kDI, wl + kWIN, kDI, tok, kDM, kDM, kDI / 2);
  }

  ln_k<false><<<kTok, kDM, 0, stream>>>(tok, lnout, fn_g, fn_b, nullptr);
  pool_k<<<kB, kDM, 0, stream>>>(lnout, pooled);
  head_k<<<kB * 4, 64, 0, stream>>>(pooled, head_w, head_b, out);
}

// Round 11
// 1266.689 us; speedup vs baseline: 1.2306x; 1.0613x over previous
//
#include <hip/hip_runtime.h>
#include <math.h>

namespace {

constexpr int kB   = 8;
constexpr int kL   = 256;
constexpr int kTok = 2048;   // B*L
constexpr int kDM  = 384;
constexpr int kDI  = 768;
constexpr int kDS  = 16;
constexpr int kDTR = 24;
constexpr int kPROJ = 56;    // DTR + 2*DS
constexpr int kNL  = 12;

constexpr int kWIN  = 2 * kDI * kDM;   // 589824 in_proj weights/layer
constexpr int kWOUT = kDM * kDI;       // 294912
constexpr int kWX   = kPROJ * kDI;     // 43008
constexpr int kWTOT = kWIN + kWOUT + kWX;  // 927744

typedef float f32x4 __attribute__((ext_vector_type(4)));
typedef short short8 __attribute__((ext_vector_type(8)));

__device__ __forceinline__ float softplus_f(float x) {
  return (x > 20.f) ? x : log1pf(__expf(x));
}
__device__ __forceinline__ float silu_f(float x) {
  return x / (1.f + __expf(-x));
}
__device__ __forceinline__ unsigned short f2bf(float f) {
  union { float f; unsigned u; } v; v.f = f;
  unsigned r = v.u + 0x7FFFu + ((v.u >> 16) & 1u);
  return (unsigned short)(r >> 16);
}
__device__ __forceinline__ float bf2f(unsigned short u) {
  return __uint_as_float((unsigned)u << 16);
}

// ------------- patch embed GEMM: tok = im2col(x)·patch_w^T + b + pos -------
__global__ __launch_bounds__(256) void patch_gemm_k(
    const float* __restrict__ x, const float* __restrict__ Bw,
    const float* __restrict__ bias, const float* __restrict__ pos,
    float* __restrict__ C) {
  __shared__ float As[16][68];
  __shared__ float Bs[16][68];
  int tid = threadIdx.x;
  int bm = blockIdx.y * 64;
  int bn = blockIdx.x * 64;
  int lr = tid >> 2;
  int lk = (tid & 3) << 2;
  int tm = (tid >> 4) << 2;
  int tn = (tid & 15) << 2;
  float acc[4][4] = {};
  for (int k0 = 0; k0 < 256; k0 += 16) {
    {
      int token = bm + lr;
      int b = token >> 8, l = token & 255;
      int h = l >> 3, w = l & 7;
      int p = k0 >> 4;
      const float* ap = x + ((size_t)(b * 512) + h * 16 + p) * 128 + w * 16 + lk;
      float4 av = *(const float4*)ap;
      As[lk + 0][lr] = av.x; As[lk + 1][lr] = av.y;
      As[lk + 2][lr] = av.z; As[lk + 3][lr] = av.w;
    }
    {
      const float* bp = Bw + (size_t)(bn + lr) * 256 + k0 + lk;
      float4 bv = *(const float4*)bp;
      Bs[lk + 0][lr] = bv.x; Bs[lk + 1][lr] = bv.y;
      Bs[lk + 2][lr] = bv.z; Bs[lk + 3][lr] = bv.w;
    }
    __syncthreads();
    #pragma unroll
    for (int k = 0; k < 16; ++k) {
      float4 a = *(const float4*)&As[k][tm];
      float4 b = *(const float4*)&Bs[k][tn];
      float av[4] = {a.x, a.y, a.z, a.w};
      float bv[4] = {b.x, b.y, b.z, b.w};
      #pragma unroll
      for (int i = 0; i < 4; ++i)
        #pragma unroll
        for (int j = 0; j < 4; ++j)
          acc[i][j] = fmaf(av[i], bv[j], acc[i][j]);
    }
    __syncthreads();
  }
  #pragma unroll
  for (int i = 0; i < 4; ++i) {
    int row = bm + tm + i;
    #pragma unroll
    for (int j = 0; j < 4; ++j) {
      int col = bn + tn + j;
      C[(size_t)row * kDM + col] =
          acc[i][j] + bias[col] + pos[(size_t)(row & 255) * kDM + col];
    }
  }
}

// ------------- final layernorm (fp32 out) ----------------------------------
__global__ __launch_bounds__(384) void ln_k(
    const float* __restrict__ in, float* __restrict__ outv,
    const float* __restrict__ g, const float* __restrict__ bb) {
  int t = blockIdx.x, d = threadIdx.x;
  float v = in[(size_t)t * kDM + d];
  float s = v, s2 = v * v;
  #pragma unroll
  for (int m = 32; m >= 1; m >>= 1) {
    s  += __shfl_xor(s, m);
    s2 += __shfl_xor(s2, m);
  }
  __shared__ float ps[6], ps2[6];
  if ((d & 63) == 0) { ps[d >> 6] = s; ps2[d >> 6] = s2; }
  __syncthreads();
  float S = 0.f, S2 = 0.f;
  #pragma unroll
  for (int i = 0; i < 6; ++i) { S += ps[i]; S2 += ps2[i]; }
  float mean = S * (1.f / 384.f);
  float var  = S2 * (1.f / 384.f) - mean * mean;
  float r = rsqrtf(var + 1e-5f);
  outv[(size_t)t * kDM + d] = (v - mean) * r * g[d] + bb[d];
}

// ------------- convert ALL layers' GEMM weights fp32 -> bf16 ---------------
__global__ __launch_bounds__(256) void convert_all_k(
    const float* __restrict__ w_in, const float* __restrict__ w_out,
    const float* __restrict__ w_x, unsigned short* __restrict__ dst) {
  int layer = blockIdx.y;
  int i4 = (blockIdx.x * 256 + threadIdx.x) * 4;
  if (i4 >= kWTOT) return;
  const float* src;
  int off;
  if (i4 < kWIN) { src = w_in + (size_t)layer * kWIN; off = i4; }
  else if (i4 < kWIN + kWOUT) { src = w_out + (size_t)layer * kWOUT; off = i4 - kWIN; }
  else { src = w_x + (size_t)layer * kWX; off = i4 - kWIN - kWOUT; }
  float4 v = *(const float4*)(src + off);
  unsigned short o[4] = {f2bf(v.x), f2bf(v.y), f2bf(v.z), f2bf(v.w)};
  *(uint2*)(dst + (size_t)layer * kWTOT + i4) = *(const uint2*)o;
}

// ------------- in_proj with fused LayerNorm (+ proj zeroing) ---------------
// xz_bf[2048,1536] = LN(tok)[2048,384] · W[1536,384]^T  (bf16 MFMA, bf16 out)
__global__ __launch_bounds__(256) void inproj_ln_k(
    const float* __restrict__ tok, const unsigned short* __restrict__ Bw,
    const float* __restrict__ g, const float* __restrict__ bb,
    unsigned short* __restrict__ Cbf, float* __restrict__ proj_zero) {
  __shared__ __align__(16) unsigned short As[4][128][8];
  __shared__ __align__(16) unsigned short Bs[4][128][8];
  __shared__ float smean[128], srstd[128];
  __shared__ float sg_[kDM], sb_[kDM];
  int tid = threadIdx.x;
  int bm = blockIdx.y * 128;
  int bn = blockIdx.x * 128;
  // proj zeroing for the upcoming split-K atomics (192 blocks cover it)
  {
    int bid = blockIdx.y * 12 + blockIdx.x;
    for (int i = bid * 256 + tid; i < kTok * kPROJ; i += 192 * 256)
      proj_zero[i] = 0.f;
  }
  for (int i = tid; i < kDM; i += 256) { sg_[i] = g[i]; sb_[i] = bb[i]; }
  // LN stats prepass: 2 threads per row
  {
    int r = tid >> 1, half = tid & 1;
    const float* rp = tok + (size_t)(bm + r) * kDM + half * 192;
    float s = 0.f, s2 = 0.f;
    #pragma unroll
    for (int q = 0; q < 48; ++q) {
      float4 v = ((const float4*)rp)[q];
      s  += v.x + v.y + v.z + v.w;
      s2 += v.x * v.x + v.y * v.y + v.z * v.z + v.w * v.w;
    }
    s  += __shfl_xor(s, 1);
    s2 += __shfl_xor(s2, 1);
    if (half == 0) {
      float mean = s * (1.f / 384.f);
      float var  = s2 * (1.f / 384.f) - mean * mean;
      smean[r] = mean;
      srstd[r] = rsqrtf(var + 1e-5f);
    }
  }
  __syncthreads();
  int wave = tid >> 6, lane = tid & 63;
  int lm = lane & 15, lq = lane >> 4;
  int wm = (wave >> 1) * 64, wn = (wave & 1) * 64;
  f32x4 acc[4][4] = {};
  for (int k0 = 0; k0 < kDM; k0 += 32) {
    int ar0 = tid & 127, aq0 = tid >> 7;
    unsigned short av[2][8];
    float mean = smean[ar0], rstd = srstd[ar0];
    #pragma unroll
    for (int gq = 0; gq < 2; ++gq) {
      int kq = aq0 + gq * 2;
      const float* ap = tok + (size_t)(bm + ar0) * kDM + k0 + kq * 8;
      float4 v0 = ((const float4*)ap)[0];
      float4 v1 = ((const float4*)ap)[1];
      float vv[8] = {v0.x, v0.y, v0.z, v0.w, v1.x, v1.y, v1.z, v1.w};
      #pragma unroll
      for (int j = 0; j < 8; ++j) {
        int k = k0 + kq * 8 + j;
        av[gq][j] = f2bf((vv[j] - mean) * rstd * sg_[k] + sb_[k]);
      }
    }
    uint4 b0 = *(const uint4*)(Bw + (size_t)(bn + ar0) * kDM + k0 + aq0 * 8);
    uint4 b1 = *(const uint4*)(Bw + (size_t)(bn + ar0) * kDM + k0 + (aq0 + 2) * 8);
    __syncthreads();
    *(uint4*)&As[aq0][ar0][0]     = *(const uint4*)av[0];
    *(uint4*)&As[aq0 + 2][ar0][0] = *(const uint4*)av[1];
    *(uint4*)&Bs[aq0][ar0][0]     = b0;
    *(uint4*)&Bs[aq0 + 2][ar0][0] = b1;
    __syncthreads();
    short8 bfrag[4];
    #pragma unroll
    for (int ni = 0; ni < 4; ++ni)
      bfrag[ni] = *(const short8*)&Bs[lq][wn + ni * 16 + lm][0];
    #pragma unroll
    for (int mi = 0; mi < 4; ++mi) {
      short8 afrag = *(const short8*)&As[lq][wm + mi * 16 + lm][0];
      #pragma unroll
      for (int ni = 0; ni < 4; ++ni)
        acc[mi][ni] = __builtin_amdgcn_mfma_f32_16x16x32_bf16(
            afrag, bfrag[ni], acc[mi][ni], 0, 0, 0);
    }
  }
  #pragma unroll
  for (int mi = 0; mi < 4; ++mi) {
    #pragma unroll
    for (int ni = 0; ni < 4; ++ni) {
      int grow0 = bm + wm + mi * 16 + lq * 4;
      int gcol = bn + wn + ni * 16 + lm;
      #pragma unroll
      for (int r = 0; r < 4; ++r)
        Cbf[(size_t)(grow0 + r) * (2 * kDI) + gcol] = f2bf(acc[mi][ni][r]);
    }
  }
}

// ------------- x_proj with fused depthwise conv + SiLU ---------------------
// A = u = silu(causal_conv4(xz[:, :768]) + cb), computed in staging.
// GEMM: proj[2048,56] += u · Wx[56,768]^T  (split-K via grid.y, atomics).
// Side output: uT_bf[b][d][l] (transposed bf16, coalesced along l).
__global__ __launch_bounds__(256) void xproj_conv_k(
    const unsigned short* __restrict__ xz, const unsigned short* __restrict__ Bw,
    const float* __restrict__ cw, const float* __restrict__ cb,
    float* __restrict__ proj, unsigned short* __restrict__ uT_bf) {
  __shared__ __align__(16) unsigned short As[4][128][8];
  __shared__ __align__(16) unsigned short Bs[4][64][8];
  __shared__ float scw[128][4];
  __shared__ float scb[128];
  int tid = threadIdx.x;
  int bm = blockIdx.x * 128;      // token tile
  int kbase = blockIdx.y * 128;   // d chunk (split-K = 6)
  int wave = tid >> 6, lane = tid & 63;
  int lm = lane & 15, lq = lane >> 4;
  int wm = wave * 32;
  f32x4 acc[2][4] = {};

  if (tid < 128) {
    *(float4*)&scw[tid][0] = *(const float4*)(cw + (size_t)(kbase + tid) * 4);
    scb[tid] = cb[kbase + tid];
  }
  __syncthreads();

  int ar0 = tid & 127;
  int aq0 = tid >> 7;   // 0 or 1
  int t = bm + ar0;
  int b = t >> 8, l = t & 255;

  for (int kt = 0; kt < 4; ++kt) {
    int k0 = kbase + kt * 32;
    unsigned short av[2][8];
    #pragma unroll
    for (int gq = 0; gq < 2; ++gq) {
      int kq = aq0 + gq * 2;
      int dloc = kt * 32 + kq * 8;
      int dg = kbase + dloc;
      float vals[4][8];
      #pragma unroll
      for (int q = 0; q < 4; ++q) {
        if (l - 3 + q >= 0) {
          uint4 r = *(const uint4*)(xz + (size_t)(t - 3 + q) * (2 * kDI) + dg);
          const unsigned short* rs = (const unsigned short*)&r;
          #pragma unroll
          for (int j = 0; j < 8; ++j) vals[q][j] = bf2f(rs[j]);
        } else {
          #pragma unroll
          for (int j = 0; j < 8; ++j) vals[q][j] = 0.f;
        }
      }
      #pragma unroll
      for (int j = 0; j < 8; ++j) {
        float a = scb[dloc + j];
        a = fmaf(vals[0][j], scw[dloc + j][0], a);
        a = fmaf(vals[1][j], scw[dloc + j][1], a);
        a = fmaf(vals[2][j], scw[dloc + j][2], a);
        a = fmaf(vals[3][j], scw[dloc + j][3], a);
        unsigned short ub = f2bf(silu_f(a));
        av[gq][j] = ub;
        // transposed side-store: lanes are consecutive l -> coalesced
        uT_bf[((size_t)b * kDI + dg + j) * kL + l] = ub;
      }
    }
    int br0 = tid & 63, bq0 = tid >> 6;
    uint4 b0;
    if (br0 < kPROJ)
      b0 = *(const uint4*)(Bw + (size_t)br0 * kDI + k0 + bq0 * 8);
    else
      b0 = make_uint4(0u, 0u, 0u, 0u);
    __syncthreads();
    *(uint4*)&As[aq0][ar0][0]     = *(const uint4*)av[0];
    *(uint4*)&As[aq0 + 2][ar0][0] = *(const uint4*)av[1];
    *(uint4*)&Bs[bq0][br0][0] = b0;
    __syncthreads();
    short8 bfrag[4];
    #pragma unroll
    for (int ni = 0; ni < 4; ++ni)
      bfrag[ni] = *(const short8*)&Bs[lq][ni * 16 + lm][0];
    #pragma unroll
    for (int mi = 0; mi < 2; ++mi) {
      short8 afrag = *(const short8*)&As[lq][wm + mi * 16 + lm][0];
      #pragma unroll
      for (int ni = 0; ni < 4; ++ni)
        acc[mi][ni] = __builtin_amdgcn_mfma_f32_16x16x32_bf16(
            afrag, bfrag[ni], acc[mi][ni], 0, 0, 0);
    }
  }

  #pragma unroll
  for (int mi = 0; mi < 2; ++mi) {
    #pragma unroll
    for (int ni = 0; ni < 4; ++ni) {
      int grow0 = bm + wm + mi * 16 + lq * 4;
      int gcol = ni * 16 + lm;
      if (gcol < kPROJ) {
        #pragma unroll
        for (int r = 0; r < 4; ++r)
          atomicAdd(&proj[(size_t)(grow0 + r) * kPROJ + gcol], acc[mi][ni][r]);
      }
    }
  }
}

// ------------- bf16 MFMA NT GEMM (out_proj): atomicAdd into residual -------
__global__ __launch_bounds__(256) void bgemm_out_k(
    const unsigned short* __restrict__ A, int lda,
    const unsigned short* __restrict__ B, int ldb,
    float* __restrict__ C, int ldc, int Kc) {
  __shared__ __align__(16) unsigned short As[4][128][8];
  __shared__ __align__(16) unsigned short Bs[4][128][8];
  int tid = threadIdx.x;
  int bm = blockIdx.y * 128;
  int bn = blockIdx.x * 128;
  int k_begin = blockIdx.z * Kc;
  int wave = tid >> 6, lane = tid & 63;
  int lm = lane & 15, lq = lane >> 4;
  int wm = (wave >> 1) * 64, wn = (wave & 1) * 64;
  f32x4 acc[4][4] = {};

  for (int kt = 0; kt < Kc; kt += 32) {
    int k0 = k_begin + kt;
    int ar0 = tid & 127, aq0 = tid >> 7;
    int aq1 = aq0 + 2;
    uint4 a0 = *(const uint4*)(A + (size_t)(bm + ar0) * lda + k0 + aq0 * 8);
    uint4 a1 = *(const uint4*)(A + (size_t)(bm + ar0) * lda + k0 + aq1 * 8);
    uint4 b0 = *(const uint4*)(B + (size_t)(bn + ar0) * ldb + k0 + aq0 * 8);
    uint4 b1 = *(const uint4*)(B + (size_t)(bn + ar0) * ldb + k0 + aq1 * 8);
    __syncthreads();
    *(uint4*)&As[aq0][ar0][0] = a0;
    *(uint4*)&As[aq1][ar0][0] = a1;
    *(uint4*)&Bs[aq0][ar0][0] = b0;
    *(uint4*)&Bs[aq1][ar0][0] = b1;
    __syncthreads();
    short8 bfrag[4];
    #pragma unroll
    for (int ni = 0; ni < 4; ++ni)
      bfrag[ni] = *(const short8*)&Bs[lq][wn + ni * 16 + lm][0];
    #pragma unroll
    for (int mi = 0; mi < 4; ++mi) {
      short8 afrag = *(const short8*)&As[lq][wm + mi * 16 + lm][0];
      #pragma unroll
      for (int ni = 0; ni < 4; ++ni)
        acc[mi][ni] = __builtin_amdgcn_mfma_f32_16x16x32_bf16(
            afrag, bfrag[ni], acc[mi][ni], 0, 0, 0);
    }
  }

  #pragma unroll
  for (int mi = 0; mi < 4; ++mi) {
    #pragma unroll
    for (int ni = 0; ni < 4; ++ni) {
      int grow0 = bm + wm + mi * 16 + lq * 4;
      int gcol = bn + wn + ni * 16 + lm;
      #pragma unroll
      for (int r = 0; r < 4; ++r)
        atomicAdd(&C[(size_t)(grow0 + r) * ldc + gcol], acc[mi][ni][r]);
    }
  }
}

// ------------- split-state register scan + fused dt_proj -------------------
// thread = (chunk c[16], state-half nh[2], dsub[8]); 8 SSM states/thread.
// u from uT_bf (bf16 transposed); z-gate computed from xz_bf directly.
__global__ __launch_bounds__(256) void scansplit_k(
    const float* __restrict__ proj, const unsigned short* __restrict__ uT_bf,
    const unsigned short* __restrict__ xz, const float* __restrict__ dtw,
    const float* __restrict__ dtb, const float* __restrict__ A_log,
    const float* __restrict__ Dsk, unsigned short* __restrict__ y_bf) {
  int d0 = blockIdx.x * 8;
  int b = blockIdx.y;
  int tid = threadIdx.x;
  int dsub = tid & 7;
  int nh = (tid >> 3) & 1;
  int c = tid >> 4;
  int d = d0 + dsub;
  __shared__ float sh[16][16][9];
  __shared__ float sca[16][16][9];

  float Av[8];
  {
    const float* ap = A_log + (size_t)d * kDS + nh * 8;
    #pragma unroll
    for (int q = 0; q < 2; ++q) {
      float4 v = ((const float4*)ap)[q];
      Av[q * 4 + 0] = -__expf(v.x);
      Av[q * 4 + 1] = -__expf(v.y);
      Av[q * 4 + 2] = -__expf(v.z);
      Av[q * 4 + 3] = -__expf(v.w);
    }
  }
  float bdt = dtb[d];
  float Dv = Dsk[d];

  const float* pr = proj + ((size_t)(b * kL) + c * 16) * kPROJ;

  // dt: my 8 tokens (l = c*16 + nh*8 + i), partner's 8 via shuffle
  float dtlo[8], dthi[8];
  {
    float wdt[24];
    const float* wp = dtw + (size_t)d * kDTR;
    #pragma unroll
    for (int q = 0; q < 6; ++q) {
      float4 v = ((const float4*)wp)[q];
      wdt[q * 4 + 0] = v.x; wdt[q * 4 + 1] = v.y;
      wdt[q * 4 + 2] = v.z; wdt[q * 4 + 3] = v.w;
    }
    const float* prm = pr + (size_t)(nh * 8) * kPROJ;
    float mine[8];
    #pragma unroll
    for (int i = 0; i < 8; ++i) {
      const float* p = prm + (size_t)i * kPROJ;
      float acc = bdt;
      #pragma unroll
      for (int q = 0; q < 6; ++q) {
        float4 v = ((const float4*)p)[q];
        acc = fmaf(v.x, wdt[q * 4 + 0], acc);
        acc = fmaf(v.y, wdt[q * 4 + 1], acc);
        acc = fmaf(v.z, wdt[q * 4 + 2], acc);
        acc = fmaf(v.w, wdt[q * 4 + 3], acc);
      }
      mine[i] = softplus_f(acc);
    }
    #pragma unroll
    for (int i = 0; i < 8; ++i) {
      float other = __shfl_xor(mine[i], 8);
      dtlo[i] = nh ? other : mine[i];
      dthi[i] = nh ? mine[i] : other;
    }
  }

  float u_[16];
  {
    const unsigned short* up = uT_bf + ((size_t)b * kDI + d) * kL + c * 16;
    uint4 v0 = ((const uint4*)up)[0];
    uint4 v1 = ((const uint4*)up)[1];
    const unsigned short* us = (const unsigned short*)&v0;
    #pragma unroll
    for (int i = 0; i < 8; ++i) u_[i] = bf2f(us[i]);
    us = (const unsigned short*)&v1;
    #pragma unroll
    for (int i = 0; i < 8; ++i) u_[8 + i] = bf2f(us[i]);
  }

  // pass 1: local chunk scan over my 8 states
  float h[8], ca[8];
  #pragma unroll
  for (int n = 0; n < 8; ++n) { h[n] = 0.f; ca[n] = 1.f; }
  #pragma unroll
  for (int i = 0; i < 16; ++i) {
    float dl = (i < 8) ? dtlo[i] : dthi[i - 8];
    float du = dl * u_[i];
    const float* p = pr + (size_t)i * kPROJ + 24 + nh * 8;
    float4 b0 = ((const float4*)p)[0];
    float4 b1 = ((const float4*)p)[1];
    float Bv[8] = {b0.x, b0.y, b0.z, b0.w, b1.x, b1.y, b1.z, b1.w};
    #pragma unroll
    for (int n = 0; n < 8; ++n) {
      float a = __expf(dl * Av[n]);
      h[n] = fmaf(a, h[n], du * Bv[n]);
      ca[n] *= a;
    }
  }
  {
    int nrow = nh * 8;
    #pragma unroll
    for (int q = 0; q < 8; ++q) {
      sh[c][nrow + q][dsub] = h[q];
      sca[c][nrow + q][dsub] = ca[q];
    }
  }
  __syncthreads();

  // chunk-prefix combine
  float h0[8];
  #pragma unroll
  for (int n = 0; n < 8; ++n) h0[n] = 0.f;
  {
    int nrow = nh * 8;
    for (int j = 0; j < c; ++j) {
      #pragma unroll
      for (int q = 0; q < 8; ++q)
        h0[q] = fmaf(sca[j][nrow + q][dsub], h0[q], sh[j][nrow + q][dsub]);
    }
  }

  // z-gate for nh==0 half (direct from xz, L2-hot)
  float sg_[16];
  if (nh == 0) {
    const unsigned short* zp =
        xz + (size_t)(b * kL + c * 16) * (2 * kDI) + kDI + d;
    #pragma unroll
    for (int i = 0; i < 16; ++i)
      sg_[i] = silu_f(bf2f(zp[(size_t)i * (2 * kDI)]));
  }

  // pass 2: true scan from h0; partial y over my 8 states; 1 shuffle; store
  unsigned short* yp = y_bf + (size_t)(b * kL + c * 16) * kDI + d;
  #pragma unroll
  for (int i = 0; i < 16; ++i) {
    float dl = (i < 8) ? dtlo[i] : dthi[i - 8];
    float du = dl * u_[i];
    const float* p = pr + (size_t)i * kPROJ + 24 + nh * 8;
    float4 b0 = ((const float4*)p)[0];
    float4 b1 = ((const float4*)p)[1];
    float4 c0 = ((const float4*)(p + 16))[0];
    float4 c1 = ((const float4*)(p + 16))[1];
    float Bv[8] = {b0.x, b0.y, b0.z, b0.w, b1.x, b1.y, b1.z, b1.w};
    float Cv[8] = {c0.x, c0.y, c0.z, c0.w, c1.x, c1.y, c1.z, c1.w};
    float yv = 0.f;
    #pragma unroll
    for (int n = 0; n < 8; ++n) {
      float a = __expf(dl * Av[n]);
      h0[n] = fmaf(a, h0[n], du * Bv[n]);
      yv = fmaf(h0[n], Cv[n], yv);
    }
    yv += __shfl_xor(yv, 8);
    if (nh == 0) yp[(size_t)i * kDI] = f2bf((yv + u_[i] * Dv) * sg_[i]);
  }
}

// ---------------- mean pool over L ----------------
__global__ __launch_bounds__(384) void pool_k(
    const float* __restrict__ h, float* __restrict__ pooled) {
  int b = blockIdx.x, d = threadIdx.x;
  float acc = 0.f;
  for (int l = 0; l < kL; ++l) acc += h[(size_t)(b * kL + l) * kDM + d];
  pooled[b * kDM + d] = acc * (1.f / 256.f);
}

// ---------------- head ----------------
__global__ __launch_bounds__(64) void head_k(
    const float* __restrict__ pooled, const float* __restrict__ hw,
    const float* __restrict__ hb, float* __restrict__ out) {
  int b = blockIdx.x >> 2, c = blockIdx.x & 3;
  int lane = threadIdx.x;
  float acc = 0.f;
  for (int dd = lane; dd < kDM; dd += 64)
    acc = fmaf(pooled[b * kDM + dd], hw[c * kDM + dd], acc);
  #pragma unroll
  for (int m = 32; m >= 1; m >>= 1) acc += __shfl_xor(acc, m);
  if (lane == 0) out[b * 4 + c] = acc + hb[c];
}

}  // namespace

extern "C" void kernel_launch(void* const* d_in, const int* in_sizes, int n_in,
                              void* d_out, int out_size, void* d_ws, size_t ws_size,
                              hipStream_t stream) {
  (void)in_sizes; (void)n_in; (void)out_size; (void)ws_size;
  const float* x        = (const float*)d_in[0];
  const float* patch_w  = (const float*)d_in[1];
  const float* patch_b  = (const float*)d_in[2];
  const float* pos      = (const float*)d_in[3];
  const float* ln_g     = (const float*)d_in[4];
  const float* ln_b     = (const float*)d_in[5];
  const float* in_w     = (const float*)d_in[6];
  const float* conv_w   = (const float*)d_in[7];
  const float* conv_b   = (const float*)d_in[8];
  const float* xproj_w  = (const float*)d_in[9];
  const float* dtproj_w = (const float*)d_in[10];
  const float* dtproj_b = (const float*)d_in[11];
  const float* A_log    = (const float*)d_in[12];
  const float* Dskip    = (const float*)d_in[13];
  const float* out_w    = (const float*)d_in[14];
  const float* fn_g     = (const float*)d_in[15];
  const float* fn_b     = (const float*)d_in[16];
  const float* head_w   = (const float*)d_in[17];
  const float* head_b   = (const float*)d_in[18];
  float* out = (float*)d_out;

  float* ws = (float*)d_ws;
  float* tok    = ws; ws += kTok * kDM;       // fp32 residual
  float* proj   = ws; ws += kTok * kPROJ;     // [t][56] row-major
  float* pooled = ws; ws += kB * kDM;
  unsigned short* xz_bf = (unsigned short*)ws; ws += kTok * 2 * kDI / 2;
  unsigned short* uT_bf = (unsigned short*)ws; ws += kTok * kDI / 2;
  unsigned short* y_bf  = (unsigned short*)ws; ws += kTok * kDI / 2;
  unsigned short* w_bf  = (unsigned short*)ws; ws += (size_t)kNL * kWTOT / 2;
  float* lnout = (float*)xz_bf;  // overlay: xz dead after last scan

  // all-layer weight cast (once per call)
  convert_all_k<<<dim3(kWTOT / 4 / 256, kNL), 256, 0, stream>>>(
      in_w, out_w, xproj_w, w_bf);

  // Patch embedding fused: im2col + GEMM + bias + pos
  patch_gemm_k<<<dim3(6, 32), 256, 0, stream>>>(x, patch_w, patch_b, pos, tok);

  for (int layer = 0; layer < kNL; ++layer) {
    const unsigned short* wl = w_bf + (size_t)layer * kWTOT;
    // in_proj with fused LN (+ proj zero): LN(tok) x W^T -> xz_bf
    inproj_ln_k<<<dim3(12, 16), 256, 0, stream>>>(
        tok, wl, ln_g + layer * kDM, ln_b + layer * kDM, xz_bf, proj);
    // x_proj with fused conv+SiLU: proj += u·Wx^T ; side out uT_bf
    xproj_conv_k<<<dim3(16, 6), 256, 0, stream>>>(
        xz_bf, wl + kWIN + kWOUT, conv_w + layer * kDI * 4,
        conv_b + layer * kDI, proj, uT_bf);
    // split-state register scan + fused dt_proj + z-gate -> y_bf
    scansplit_k<<<dim3(kDI / 8, kB), 256, 0, stream>>>(
        proj, uT_bf, xz_bf, dtproj_w + (size_t)layer * kDI * kDTR,
        dtproj_b + layer * kDI, A_log + (size_t)layer * kDI * kDS,
        Dskip + layer * kDI, y_bf);
    // out_proj (MFMA, split-K=2, atomic into residual): tok += y x W^T
    bgemm_out_k<<<dim3(3, 16, 2), 256, 0, stream>>>(
        y_bf, kDI, wl + kWIN, kDI, tok, kDM, kDI / 2);
  }

  ln_k<<<kTok, kDM, 0, stream>>>(tok, lnout, fn_g, fn_b);
  pool_k<<<kB, kDM, 0, stream>>>(lnout, pooled);
  head_k<<<kB * 4, 64, 0, stream>>>(pooled, head_w, head_b, out);
}

// Round 12
// 1146.635 us; speedup vs baseline: 1.3594x; 1.1047x over previous
//
#include <hip/hip_runtime.h>
#include <math.h>

namespace {

constexpr int kB   = 8;
constexpr int kL   = 256;
constexpr int kTok = 2048;   // B*L
constexpr int kDM  = 384;
constexpr int kDI  = 768;
constexpr int kDS  = 16;
constexpr int kDTR = 24;
constexpr int kPROJ = 56;    // DTR + 2*DS
constexpr int kNL  = 12;

constexpr int kWIN  = 2 * kDI * kDM;   // 589824 in_proj weights/layer
constexpr int kWOUT = kDM * kDI;       // 294912
constexpr int kWX   = kPROJ * kDI;     // 43008
constexpr int kWTOT = kWIN + kWOUT + kWX;  // 927744

typedef float f32x4 __attribute__((ext_vector_type(4)));
typedef short short8 __attribute__((ext_vector_type(8)));

__device__ __forceinline__ float softplus_f(float x) {
  return (x > 20.f) ? x : log1pf(__expf(x));
}
__device__ __forceinline__ float silu_f(float x) {
  return x / (1.f + __expf(-x));
}
__device__ __forceinline__ unsigned short f2bf(float f) {
  union { float f; unsigned u; } v; v.f = f;
  unsigned r = v.u + 0x7FFFu + ((v.u >> 16) & 1u);
  return (unsigned short)(r >> 16);
}
__device__ __forceinline__ float bf2f(unsigned short u) {
  return __uint_as_float((unsigned)u << 16);
}

// ------------- patch embed GEMM: tok = im2col(x)·patch_w^T + b + pos -------
__global__ __launch_bounds__(256) void patch_gemm_k(
    const float* __restrict__ x, const float* __restrict__ Bw,
    const float* __restrict__ bias, const float* __restrict__ pos,
    float* __restrict__ C) {
  __shared__ float As[16][68];
  __shared__ float Bs[16][68];
  int tid = threadIdx.x;
  int bm = blockIdx.y * 64;
  int bn = blockIdx.x * 64;
  int lr = tid >> 2;
  int lk = (tid & 3) << 2;
  int tm = (tid >> 4) << 2;
  int tn = (tid & 15) << 2;
  float acc[4][4] = {};
  for (int k0 = 0; k0 < 256; k0 += 16) {
    {
      int token = bm + lr;
      int b = token >> 8, l = token & 255;
      int h = l >> 3, w = l & 7;
      int p = k0 >> 4;
      const float* ap = x + ((size_t)(b * 512) + h * 16 + p) * 128 + w * 16 + lk;
      float4 av = *(const float4*)ap;
      As[lk + 0][lr] = av.x; As[lk + 1][lr] = av.y;
      As[lk + 2][lr] = av.z; As[lk + 3][lr] = av.w;
    }
    {
      const float* bp = Bw + (size_t)(bn + lr) * 256 + k0 + lk;
      float4 bv = *(const float4*)bp;
      Bs[lk + 0][lr] = bv.x; Bs[lk + 1][lr] = bv.y;
      Bs[lk + 2][lr] = bv.z; Bs[lk + 3][lr] = bv.w;
    }
    __syncthreads();
    #pragma unroll
    for (int k = 0; k < 16; ++k) {
      float4 a = *(const float4*)&As[k][tm];
      float4 b = *(const float4*)&Bs[k][tn];
      float av[4] = {a.x, a.y, a.z, a.w};
      float bv[4] = {b.x, b.y, b.z, b.w};
      #pragma unroll
      for (int i = 0; i < 4; ++i)
        #pragma unroll
        for (int j = 0; j < 4; ++j)
          acc[i][j] = fmaf(av[i], bv[j], acc[i][j]);
    }
    __syncthreads();
  }
  #pragma unroll
  for (int i = 0; i < 4; ++i) {
    int row = bm + tm + i;
    #pragma unroll
    for (int j = 0; j < 4; ++j) {
      int col = bn + tn + j;
      C[(size_t)row * kDM + col] =
          acc[i][j] + bias[col] + pos[(size_t)(row & 255) * kDM + col];
    }
  }
}

// ------------- final layernorm + fused mean-pool (atomicAdd) ---------------
__global__ __launch_bounds__(384) void lnpool_k(
    const float* __restrict__ in, float* __restrict__ pooled,
    const float* __restrict__ g, const float* __restrict__ bb) {
  int t = blockIdx.x, d = threadIdx.x;
  float v = in[(size_t)t * kDM + d];
  float s = v, s2 = v * v;
  #pragma unroll
  for (int m = 32; m >= 1; m >>= 1) {
    s  += __shfl_xor(s, m);
    s2 += __shfl_xor(s2, m);
  }
  __shared__ float ps[6], ps2[6];
  if ((d & 63) == 0) { ps[d >> 6] = s; ps2[d >> 6] = s2; }
  __syncthreads();
  float S = 0.f, S2 = 0.f;
  #pragma unroll
  for (int i = 0; i < 6; ++i) { S += ps[i]; S2 += ps2[i]; }
  float mean = S * (1.f / 384.f);
  float var  = S2 * (1.f / 384.f) - mean * mean;
  float r = rsqrtf(var + 1e-5f);
  float o = (v - mean) * r * g[d] + bb[d];
  atomicAdd(&pooled[(size_t)(t >> 8) * kDM + d], o * (1.f / 256.f));
}

// ------------- convert ALL layers' GEMM weights fp32 -> bf16 (+pool zero) --
__global__ __launch_bounds__(256) void convert_all_k(
    const float* __restrict__ w_in, const float* __restrict__ w_out,
    const float* __restrict__ w_x, unsigned short* __restrict__ dst,
    float* __restrict__ pooled_zero) {
  int layer = blockIdx.y;
  int tid = threadIdx.x;
  if (layer == 0 && blockIdx.x == 0) {
    for (int i = tid; i < kB * kDM; i += 256) pooled_zero[i] = 0.f;
  }
  int i4 = (blockIdx.x * 256 + tid) * 4;
  if (i4 >= kWTOT) return;
  const float* src;
  int off;
  if (i4 < kWIN) { src = w_in + (size_t)layer * kWIN; off = i4; }
  else if (i4 < kWIN + kWOUT) { src = w_out + (size_t)layer * kWOUT; off = i4 - kWIN; }
  else { src = w_x + (size_t)layer * kWX; off = i4 - kWIN - kWOUT; }
  float4 v = *(const float4*)(src + off);
  unsigned short o[4] = {f2bf(v.x), f2bf(v.y), f2bf(v.z), f2bf(v.w)};
  *(uint2*)(dst + (size_t)layer * kWTOT + i4) = *(const uint2*)o;
}

// ------------- in_proj with fused LayerNorm (+ proj zeroing), 64x128 -------
// xz_bf[2048,1536] = LN(tok)[2048,384] · W[1536,384]^T  (bf16 MFMA, bf16 out)
// grid (12, 32) = 384 blocks.
__global__ __launch_bounds__(256) void inproj_ln_k(
    const float* __restrict__ tok, const unsigned short* __restrict__ Bw,
    const float* __restrict__ g, const float* __restrict__ bb,
    unsigned short* __restrict__ Cbf, float* __restrict__ proj_zero) {
  __shared__ __align__(16) unsigned short As[4][64][8];
  __shared__ __align__(16) unsigned short Bs[4][128][8];
  __shared__ float smean[64], srstd[64];
  __shared__ float sg_[kDM], sb_[kDM];
  int tid = threadIdx.x;
  int bm = blockIdx.y * 64;
  int bn = blockIdx.x * 128;
  // proj zeroing for the upcoming split-K atomics (384 blocks cover it)
  {
    int bid = blockIdx.y * 12 + blockIdx.x;
    for (int i = bid * 256 + tid; i < kTok * kPROJ; i += 384 * 256)
      proj_zero[i] = 0.f;
  }
  for (int i = tid; i < kDM; i += 256) { sg_[i] = g[i]; sb_[i] = bb[i]; }
  // LN stats prepass: 4 threads per row
  {
    int r = tid >> 2, quarter = tid & 3;
    const float* rp = tok + (size_t)(bm + r) * kDM + quarter * 96;
    float s = 0.f, s2 = 0.f;
    #pragma unroll
    for (int q = 0; q < 24; ++q) {
      float4 v = ((const float4*)rp)[q];
      s  += v.x + v.y + v.z + v.w;
      s2 += v.x * v.x + v.y * v.y + v.z * v.z + v.w * v.w;
    }
    s  += __shfl_xor(s, 1);  s2 += __shfl_xor(s2, 1);
    s  += __shfl_xor(s, 2);  s2 += __shfl_xor(s2, 2);
    if (quarter == 0) {
      float mean = s * (1.f / 384.f);
      float var  = s2 * (1.f / 384.f) - mean * mean;
      smean[r] = mean;
      srstd[r] = rsqrtf(var + 1e-5f);
    }
  }
  __syncthreads();
  int wave = tid >> 6, lane = tid & 63;
  int lm = lane & 15, lq = lane >> 4;
  int wm = (wave & 1) * 32, wn = (wave >> 1) * 64;
  f32x4 acc[2][4] = {};
  for (int k0 = 0; k0 < kDM; k0 += 32) {
    int ar = tid & 63, aq = tid >> 6;  // aq 0..3 (k-quad)
    unsigned short av[8];
    {
      float mean = smean[ar], rstd = srstd[ar];
      const float* ap = tok + (size_t)(bm + ar) * kDM + k0 + aq * 8;
      float4 v0 = ((const float4*)ap)[0];
      float4 v1 = ((const float4*)ap)[1];
      float vv[8] = {v0.x, v0.y, v0.z, v0.w, v1.x, v1.y, v1.z, v1.w};
      #pragma unroll
      for (int j = 0; j < 8; ++j) {
        int k = k0 + aq * 8 + j;
        av[j] = f2bf((vv[j] - mean) * rstd * sg_[k] + sb_[k]);
      }
    }
    int br = tid & 127, bq0 = tid >> 7, bq1 = bq0 + 2;
    uint4 b0 = *(const uint4*)(Bw + (size_t)(bn + br) * kDM + k0 + bq0 * 8);
    uint4 b1 = *(const uint4*)(Bw + (size_t)(bn + br) * kDM + k0 + bq1 * 8);
    __syncthreads();
    *(uint4*)&As[aq][ar][0]  = *(const uint4*)av;
    *(uint4*)&Bs[bq0][br][0] = b0;
    *(uint4*)&Bs[bq1][br][0] = b1;
    __syncthreads();
    short8 bfrag[4];
    #pragma unroll
    for (int ni = 0; ni < 4; ++ni)
      bfrag[ni] = *(const short8*)&Bs[lq][wn + ni * 16 + lm][0];
    #pragma unroll
    for (int mi = 0; mi < 2; ++mi) {
      short8 afrag = *(const short8*)&As[lq][wm + mi * 16 + lm][0];
      #pragma unroll
      for (int ni = 0; ni < 4; ++ni)
        acc[mi][ni] = __builtin_amdgcn_mfma_f32_16x16x32_bf16(
            afrag, bfrag[ni], acc[mi][ni], 0, 0, 0);
    }
  }
  #pragma unroll
  for (int mi = 0; mi < 2; ++mi) {
    #pragma unroll
    for (int ni = 0; ni < 4; ++ni) {
      int grow0 = bm + wm + mi * 16 + lq * 4;
      int gcol = bn + wn + ni * 16 + lm;
      #pragma unroll
      for (int r = 0; r < 4; ++r)
        Cbf[(size_t)(grow0 + r) * (2 * kDI) + gcol] = f2bf(acc[mi][ni][r]);
    }
  }
}

// ------------- x_proj with fused depthwise conv + SiLU, BM=64 --------------
// grid (32, 6) = 192 blocks. Side output uT_bf[b][d][l] bf16 transposed.
__global__ __launch_bounds__(256) void xproj_conv_k(
    const unsigned short* __restrict__ xz, const unsigned short* __restrict__ Bw,
    const float* __restrict__ cw, const float* __restrict__ cb,
    float* __restrict__ proj, unsigned short* __restrict__ uT_bf) {
  __shared__ __align__(16) unsigned short As[4][64][8];
  __shared__ __align__(16) unsigned short Bs[4][64][8];
  __shared__ float scw[128][4];
  __shared__ float scb[128];
  int tid = threadIdx.x;
  int bm = blockIdx.x * 64;       // token tile
  int kbase = blockIdx.y * 128;   // d chunk (split-K = 6)
  int wave = tid >> 6, lane = tid & 63;
  int lm = lane & 15, lq = lane >> 4;
  int wm = wave * 16;
  f32x4 acc[4] = {};

  if (tid < 128) {
    *(float4*)&scw[tid][0] = *(const float4*)(cw + (size_t)(kbase + tid) * 4);
    scb[tid] = cb[kbase + tid];
  }
  __syncthreads();

  int ar = tid & 63;
  int aq = tid >> 6;   // 0..3
  int t = bm + ar;
  int b = t >> 8, l = t & 255;

  for (int kt = 0; kt < 4; ++kt) {
    int k0 = kbase + kt * 32;
    int dloc = kt * 32 + aq * 8;
    int dg = kbase + dloc;
    unsigned short av[8];
    {
      float vals[4][8];
      #pragma unroll
      for (int q = 0; q < 4; ++q) {
        if (l - 3 + q >= 0) {
          uint4 r = *(const uint4*)(xz + (size_t)(t - 3 + q) * (2 * kDI) + dg);
          const unsigned short* rs = (const unsigned short*)&r;
          #pragma unroll
          for (int j = 0; j < 8; ++j) vals[q][j] = bf2f(rs[j]);
        } else {
          #pragma unroll
          for (int j = 0; j < 8; ++j) vals[q][j] = 0.f;
        }
      }
      #pragma unroll
      for (int j = 0; j < 8; ++j) {
        float a = scb[dloc + j];
        a = fmaf(vals[0][j], scw[dloc + j][0], a);
        a = fmaf(vals[1][j], scw[dloc + j][1], a);
        a = fmaf(vals[2][j], scw[dloc + j][2], a);
        a = fmaf(vals[3][j], scw[dloc + j][3], a);
        unsigned short ub = f2bf(silu_f(a));
        av[j] = ub;
        uT_bf[((size_t)b * kDI + dg + j) * kL + l] = ub;
      }
    }
    int br = tid & 63, bq = tid >> 6;
    uint4 b0;
    if (br < kPROJ)
      b0 = *(const uint4*)(Bw + (size_t)br * kDI + k0 + bq * 8);
    else
      b0 = make_uint4(0u, 0u, 0u, 0u);
    __syncthreads();
    *(uint4*)&As[aq][ar][0] = *(const uint4*)av;
    *(uint4*)&Bs[bq][br][0] = b0;
    __syncthreads();
    short8 afrag = *(const short8*)&As[lq][wm + lm][0];
    #pragma unroll
    for (int ni = 0; ni < 4; ++ni) {
      short8 bfrag = *(const short8*)&Bs[lq][ni * 16 + lm][0];
      acc[ni] = __builtin_amdgcn_mfma_f32_16x16x32_bf16(
          afrag, bfrag, acc[ni], 0, 0, 0);
    }
  }

  #pragma unroll
  for (int ni = 0; ni < 4; ++ni) {
    int grow0 = bm + wm + lq * 4;
    int gcol = ni * 16 + lm;
    if (gcol < kPROJ) {
      #pragma unroll
      for (int r = 0; r < 4; ++r)
        atomicAdd(&proj[(size_t)(grow0 + r) * kPROJ + gcol], acc[ni][r]);
    }
  }
}

// ------------- bf16 MFMA NT GEMM (out_proj): atomicAdd into residual -------
__global__ __launch_bounds__(256) void bgemm_out_k(
    const unsigned short* __restrict__ A, int lda,
    const unsigned short* __restrict__ B, int ldb,
    float* __restrict__ C, int ldc, int Kc) {
  __shared__ __align__(16) unsigned short As[4][128][8];
  __shared__ __align__(16) unsigned short Bs[4][128][8];
  int tid = threadIdx.x;
  int bm = blockIdx.y * 128;
  int bn = blockIdx.x * 128;
  int k_begin = blockIdx.z * Kc;
  int wave = tid >> 6, lane = tid & 63;
  int lm = lane & 15, lq = lane >> 4;
  int wm = (wave >> 1) * 64, wn = (wave & 1) * 64;
  f32x4 acc[4][4] = {};

  for (int kt = 0; kt < Kc; kt += 32) {
    int k0 = k_begin + kt;
    int ar0 = tid & 127, aq0 = tid >> 7;
    int aq1 = aq0 + 2;
    uint4 a0 = *(const uint4*)(A + (size_t)(bm + ar0) * lda + k0 + aq0 * 8);
    uint4 a1 = *(const uint4*)(A + (size_t)(bm + ar0) * lda + k0 + aq1 * 8);
    uint4 b0 = *(const uint4*)(B + (size_t)(bn + ar0) * ldb + k0 + aq0 * 8);
    uint4 b1 = *(const uint4*)(B + (size_t)(bn + ar0) * ldb + k0 + aq1 * 8);
    __syncthreads();
    *(uint4*)&As[aq0][ar0][0] = a0;
    *(uint4*)&As[aq1][ar0][0] = a1;
    *(uint4*)&Bs[aq0][ar0][0] = b0;
    *(uint4*)&Bs[aq1][ar0][0] = b1;
    __syncthreads();
    short8 bfrag[4];
    #pragma unroll
    for (int ni = 0; ni < 4; ++ni)
      bfrag[ni] = *(const short8*)&Bs[lq][wn + ni * 16 + lm][0];
    #pragma unroll
    for (int mi = 0; mi < 4; ++mi) {
      short8 afrag = *(const short8*)&As[lq][wm + mi * 16 + lm][0];
      #pragma unroll
      for (int ni = 0; ni < 4; ++ni)
        acc[mi][ni] = __builtin_amdgcn_mfma_f32_16x16x32_bf16(
            afrag, bfrag[ni], acc[mi][ni], 0, 0, 0);
    }
  }

  #pragma unroll
  for (int mi = 0; mi < 4; ++mi) {
    #pragma unroll
    for (int ni = 0; ni < 4; ++ni) {
      int grow0 = bm + wm + mi * 16 + lq * 4;
      int gcol = bn + wn + ni * 16 + lm;
      #pragma unroll
      for (int r = 0; r < 4; ++r)
        atomicAdd(&C[(size_t)(grow0 + r) * ldc + gcol], acc[mi][ni][r]);
    }
  }
}

// ------------- split-state register scan + fused dt_proj -------------------
// thread = (chunk c[16], state-half nh[2], dsub[8]); 8 SSM states/thread.
__global__ __launch_bounds__(256) void scansplit_k(
    const float* __restrict__ proj, const unsigned short* __restrict__ uT_bf,
    const unsigned short* __restrict__ xz, const float* __restrict__ dtw,
    const float* __restrict__ dtb, const float* __restrict__ A_log,
    const float* __restrict__ Dsk, unsigned short* __restrict__ y_bf) {
  int d0 = blockIdx.x * 8;
  int b = blockIdx.y;
  int tid = threadIdx.x;
  int dsub = tid & 7;
  int nh = (tid >> 3) & 1;
  int c = tid >> 4;
  int d = d0 + dsub;
  __shared__ float sh[16][16][9];
  __shared__ float sca[16][16][9];

  float Av[8];
  {
    const float* ap = A_log + (size_t)d * kDS + nh * 8;
    #pragma unroll
    for (int q = 0; q < 2; ++q) {
      float4 v = ((const float4*)ap)[q];
      Av[q * 4 + 0] = -__expf(v.x);
      Av[q * 4 + 1] = -__expf(v.y);
      Av[q * 4 + 2] = -__expf(v.z);
      Av[q * 4 + 3] = -__expf(v.w);
    }
  }
  float bdt = dtb[d];
  float Dv = Dsk[d];

  const float* pr = proj + ((size_t)(b * kL) + c * 16) * kPROJ;

  // dt: my 8 tokens (l = c*16 + nh*8 + i), partner's 8 via shuffle
  float dtlo[8], dthi[8];
  {
    float wdt[24];
    const float* wp = dtw + (size_t)d * kDTR;
    #pragma unroll
    for (int q = 0; q < 6; ++q) {
      float4 v = ((const float4*)wp)[q];
      wdt[q * 4 + 0] = v.x; wdt[q * 4 + 1] = v.y;
      wdt[q * 4 + 2] = v.z; wdt[q * 4 + 3] = v.w;
    }
    const float* prm = pr + (size_t)(nh * 8) * kPROJ;
    float mine[8];
    #pragma unroll
    for (int i = 0; i < 8; ++i) {
      const float* p = prm + (size_t)i * kPROJ;
      float acc = bdt;
      #pragma unroll
      for (int q = 0; q < 6; ++q) {
        float4 v = ((const float4*)p)[q];
        acc = fmaf(v.x, wdt[q * 4 + 0], acc);
        acc = fmaf(v.y, wdt[q * 4 + 1], acc);
        acc = fmaf(v.z, wdt[q * 4 + 2], acc);
        acc = fmaf(v.w, wdt[q * 4 + 3], acc);
      }
      mine[i] = softplus_f(acc);
    }
    #pragma unroll
    for (int i = 0; i < 8; ++i) {
      float other = __shfl_xor(mine[i], 8);
      dtlo[i] = nh ? other : mine[i];
      dthi[i] = nh ? mine[i] : other;
    }
  }

  float u_[16];
  {
    const unsigned short* up = uT_bf + ((size_t)b * kDI + d) * kL + c * 16;
    uint4 v0 = ((const uint4*)up)[0];
    uint4 v1 = ((const uint4*)up)[1];
    const unsigned short* us = (const unsigned short*)&v0;
    #pragma unroll
    for (int i = 0; i < 8; ++i) u_[i] = bf2f(us[i]);
    us = (const unsigned short*)&v1;
    #pragma unroll
    for (int i = 0; i < 8; ++i) u_[8 + i] = bf2f(us[i]);
  }

  // pass 1: local chunk scan over my 8 states
  float h[8], ca[8];
  #pragma unroll
  for (int n = 0; n < 8; ++n) { h[n] = 0.f; ca[n] = 1.f; }
  #pragma unroll
  for (int i = 0; i < 16; ++i) {
    float dl = (i < 8) ? dtlo[i] : dthi[i - 8];
    float du = dl * u_[i];
    const float* p = pr + (size_t)i * kPROJ + 24 + nh * 8;
    float4 b0 = ((const float4*)p)[0];
    float4 b1 = ((const float4*)p)[1];
    float Bv[8] = {b0.x, b0.y, b0.z, b0.w, b1.x, b1.y, b1.z, b1.w};
    #pragma unroll
    for (int n = 0; n < 8; ++n) {
      float a = __expf(dl * Av[n]);
      h[n] = fmaf(a, h[n], du * Bv[n]);
      ca[n] *= a;
    }
  }
  {
    int nrow = nh * 8;
    #pragma unroll
    for (int q = 0; q < 8; ++q) {
      sh[c][nrow + q][dsub] = h[q];
      sca[c][nrow + q][dsub] = ca[q];
    }
  }
  __syncthreads();

  // chunk-prefix combine
  float h0[8];
  #pragma unroll
  for (int n = 0; n < 8; ++n) h0[n] = 0.f;
  {
    int nrow = nh * 8;
    for (int j = 0; j < c; ++j) {
      #pragma unroll
      for (int q = 0; q < 8; ++q)
        h0[q] = fmaf(sca[j][nrow + q][dsub], h0[q], sh[j][nrow + q][dsub]);
    }
  }

  // z-gate for nh==0 half (direct from xz, L2-hot)
  float sg_[16];
  if (nh == 0) {
    const unsigned short* zp =
        xz + (size_t)(b * kL + c * 16) * (2 * kDI) + kDI + d;
    #pragma unroll
    for (int i = 0; i < 16; ++i)
      sg_[i] = silu_f(bf2f(zp[(size_t)i * (2 * kDI)]));
  }

  // pass 2: true scan from h0; partial y over my 8 states; 1 shuffle; store
  unsigned short* yp = y_bf + (size_t)(b * kL + c * 16) * kDI + d;
  #pragma unroll
  for (int i = 0; i < 16; ++i) {
    float dl = (i < 8) ? dtlo[i] : dthi[i - 8];
    float du = dl * u_[i];
    const float* p = pr + (size_t)i * kPROJ + 24 + nh * 8;
    float4 b0 = ((const float4*)p)[0];
    float4 b1 = ((const float4*)p)[1];
    float4 c0 = ((const float4*)(p + 16))[0];
    float4 c1 = ((const float4*)(p + 16))[1];
    float Bv[8] = {b0.x, b0.y, b0.z, b0.w, b1.x, b1.y, b1.z, b1.w};
    float Cv[8] = {c0.x, c0.y, c0.z, c0.w, c1.x, c1.y, c1.z, c1.w};
    float yv = 0.f;
    #pragma unroll
    for (int n = 0; n < 8; ++n) {
      float a = __expf(dl * Av[n]);
      h0[n] = fmaf(a, h0[n], du * Bv[n]);
      yv = fmaf(h0[n], Cv[n], yv);
    }
    yv += __shfl_xor(yv, 8);
    if (nh == 0) yp[(size_t)i * kDI] = f2bf((yv + u_[i] * Dv) * sg_[i]);
  }
}

// ---------------- head ----------------
__global__ __launch_bounds__(64) void head_k(
    const float* __restrict__ pooled, const float* __restrict__ hw,
    const float* __restrict__ hb, float* __restrict__ out) {
  int b = blockIdx.x >> 2, c = blockIdx.x & 3;
  int lane = threadIdx.x;
  float acc = 0.f;
  for (int dd = lane; dd < kDM; dd += 64)
    acc = fmaf(pooled[b * kDM + dd], hw[c * kDM + dd], acc);
  #pragma unroll
  for (int m = 32; m >= 1; m >>= 1) acc += __shfl_xor(acc, m);
  if (lane == 0) out[b * 4 + c] = acc + hb[c];
}

}  // namespace

extern "C" void kernel_launch(void* const* d_in, const int* in_sizes, int n_in,
                              void* d_out, int out_size, void* d_ws, size_t ws_size,
                              hipStream_t stream) {
  (void)in_sizes; (void)n_in; (void)out_size; (void)ws_size;
  const float* x        = (const float*)d_in[0];
  const float* patch_w  = (const float*)d_in[1];
  const float* patch_b  = (const float*)d_in[2];
  const float* pos      = (const float*)d_in[3];
  const float* ln_g     = (const float*)d_in[4];
  const float* ln_b     = (const float*)d_in[5];
  const float* in_w     = (const float*)d_in[6];
  const float* conv_w   = (const float*)d_in[7];
  const float* conv_b   = (const float*)d_in[8];
  const float* xproj_w  = (const float*)d_in[9];
  const float* dtproj_w = (const float*)d_in[10];
  const float* dtproj_b = (const float*)d_in[11];
  const float* A_log    = (const float*)d_in[12];
  const float* Dskip    = (const float*)d_in[13];
  const float* out_w    = (const float*)d_in[14];
  const float* fn_g     = (const float*)d_in[15];
  const float* fn_b     = (const float*)d_in[16];
  const float* head_w   = (const float*)d_in[17];
  const float* head_b   = (const float*)d_in[18];
  float* out = (float*)d_out;

  float* ws = (float*)d_ws;
  float* tok    = ws; ws += kTok * kDM;       // fp32 residual
  float* proj   = ws; ws += kTok * kPROJ;     // [t][56] row-major
  float* pooled = ws; ws += kB * kDM;
  unsigned short* xz_bf = (unsigned short*)ws; ws += kTok * 2 * kDI / 2;
  unsigned short* uT_bf = (unsigned short*)ws; ws += kTok * kDI / 2;
  unsigned short* y_bf  = (unsigned short*)ws; ws += kTok * kDI / 2;
  unsigned short* w_bf  = (unsigned short*)ws; ws += (size_t)kNL * kWTOT / 2;

  // all-layer weight cast + pooled zero-init (once per call)
  convert_all_k<<<dim3(kWTOT / 4 / 256, kNL), 256, 0, stream>>>(
      in_w, out_w, xproj_w, w_bf, pooled);

  // Patch embedding fused: im2col + GEMM + bias + pos
  patch_gemm_k<<<dim3(6, 32), 256, 0, stream>>>(x, patch_w, patch_b, pos, tok);

  for (int layer = 0; layer < kNL; ++layer) {
    const unsigned short* wl = w_bf + (size_t)layer * kWTOT;
    // in_proj with fused LN (+ proj zero): LN(tok) x W^T -> xz_bf  (384 blk)
    inproj_ln_k<<<dim3(12, 32), 256, 0, stream>>>(
        tok, wl, ln_g + layer * kDM, ln_b + layer * kDM, xz_bf, proj);
    // x_proj with fused conv+SiLU: proj += u·Wx^T ; side out uT_bf (192 blk)
    xproj_conv_k<<<dim3(32, 6), 256, 0, stream>>>(
        xz_bf, wl + kWIN + kWOUT, conv_w + layer * kDI * 4,
        conv_b + layer * kDI, proj, uT_bf);
    // split-state register scan + fused dt_proj + z-gate -> y_bf
    scansplit_k<<<dim3(kDI / 8, kB), 256, 0, stream>>>(
        proj, uT_bf, xz_bf, dtproj_w + (size_t)layer * kDI * kDTR,
        dtproj_b + layer * kDI, A_log + (size_t)layer * kDI * kDS,
        Dskip + layer * kDI, y_bf);
    // out_proj (MFMA, split-K=4, atomic into residual): tok += y x W^T
    bgemm_out_k<<<dim3(3, 16, 4), 256, 0, stream>>>(
        y_bf, kDI, wl + kWIN, kDI, tok, kDM, kDI / 4);
  }

  // final LN + fused mean-pool (atomicAdd into pre-zeroed pooled)
  lnpool_k<<<kTok, kDM, 0, stream>>>(tok, pooled, fn_g, fn_b);
  head_k<<<kB * 4, 64, 0, stream>>>(pooled, head_w, head_b, out);
}